// Round 12
// baseline (16693.872 us; speedup 1.0000x reference)
//
#include <hip/hip_runtime.h>
#include <stdint.h>

// ---------------------------------------------------------------------------
// R19 = R15/R18 with the acquire-inv REMOVED and h reads made coherent+batched.
//   Four sync/data variants (R15 9.95 / R16 10.5 / R17 10.4 / R18 10.07) all
//   landed ~10ms -> shared cost: per-phase acquire-inv + post-inv refill (+
//   variance-driven max-of-64 skew). R14 proved no-inv semantics correct but
//   paid 16 SERIALIZED coherence RTTs (loads consumed pair-by-pair) = 18.3us.
//   R19 batches 32 independent system-scope b64 h-loads BEFORE the MFMA loop
//   (one pipelined RTT), keeps system-scope b64-packed h stores, and strips
//   the acquire from the R15 leader/go barrier. L2 is never invalidated:
//   weights/E0/xh/xf stay resident across all 865 phases.
//   Ordering (R14-proven): system h-stores acked at the coherence point ->
//   vmcnt(0) drain in __syncthreads -> arrival agent-RMW at the same point ->
//   leader detects -> go store (system) -> pollers' system load sees go ->
//   consumers' system loads served at the coherence point = fresh. No wbl2,
//   no inv, anywhere.
// ---------------------------------------------------------------------------

typedef __attribute__((ext_vector_type(8))) short bfx8;   // 8 bf16 (4 VGPRs)
typedef __attribute__((ext_vector_type(4))) float fx4;

#define NBLK 128
#define NTHR 512
#define BH   (256*512)

__device__ __forceinline__ unsigned short f2bf(float f){
  unsigned u = __float_as_uint(f);
  u += 0x7FFFu + ((u >> 16) & 1u);          // RNE
  return (unsigned short)(u >> 16);
}
__device__ __forceinline__ float bf2f(unsigned short b){
  return __uint_as_float(((unsigned)b) << 16);
}
__device__ __forceinline__ float sigm(float x){ return 1.0f/(1.0f + __expf(-x)); }
__device__ __forceinline__ float tanhf_(float x){
  x = fminf(12.0f, fmaxf(-12.0f, x));
  float e = __expf(2.0f*x);
  return (e - 1.0f)/(e + 1.0f);
}

// 64-block supergroup barrier, leader/go (R15 structure) WITHOUT acquire-inv.
__device__ __forceinline__ bool groupbar(unsigned* cntg, int sub, unsigned gen,
                                         unsigned* go, bool leader,
                                         unsigned* abortf, volatile unsigned* s_abort){
  __syncthreads();
  if (threadIdx.x == 0){
    __hip_atomic_fetch_add(cntg + sub*32, 1u, __ATOMIC_RELAXED, __HIP_MEMORY_SCOPE_AGENT);
    const unsigned target = gen*16u;
    unsigned spins = 0;
    if (leader){
      for (;;){
        unsigned v0 = __hip_atomic_fetch_add(cntg +  0, 0u, __ATOMIC_RELAXED, __HIP_MEMORY_SCOPE_AGENT);
        unsigned v1 = __hip_atomic_fetch_add(cntg + 32, 0u, __ATOMIC_RELAXED, __HIP_MEMORY_SCOPE_AGENT);
        unsigned v2 = __hip_atomic_fetch_add(cntg + 64, 0u, __ATOMIC_RELAXED, __HIP_MEMORY_SCOPE_AGENT);
        unsigned v3 = __hip_atomic_fetch_add(cntg + 96, 0u, __ATOMIC_RELAXED, __HIP_MEMORY_SCOPE_AGENT);
        if (v0 >= target && v1 >= target && v2 >= target && v3 >= target) break;
        if (((++spins) & 1023u) == 0u){
          if (__hip_atomic_load(abortf, __ATOMIC_RELAXED, __HIP_MEMORY_SCOPE_AGENT) != 0u){
            *s_abort = 1u; break;
          }
          if (spins > (1u << 20)){
            __hip_atomic_store(abortf, 1u, __ATOMIC_RELAXED, __HIP_MEMORY_SCOPE_AGENT);
            *s_abort = 1u; break;
          }
        }
        __builtin_amdgcn_s_sleep(2);
      }
      __hip_atomic_store(go, gen, __ATOMIC_RELAXED, __HIP_MEMORY_SCOPE_SYSTEM);
    } else {
      while (__hip_atomic_load(go, __ATOMIC_RELAXED, __HIP_MEMORY_SCOPE_SYSTEM) < gen){
        if (((++spins) & 1023u) == 0u){
          if (__hip_atomic_load(abortf, __ATOMIC_RELAXED, __HIP_MEMORY_SCOPE_AGENT) != 0u){
            *s_abort = 1u; break;
          }
          if (spins > (1u << 20)){
            __hip_atomic_store(abortf, 1u, __ATOMIC_RELAXED, __HIP_MEMORY_SCOPE_AGENT);
            *s_abort = 1u; break;
          }
        }
        __builtin_amdgcn_s_sleep(2);
      }
    }
    // no acquire, no inv: h traffic is system-scope (coherence-point direct)
  }
  __syncthreads();
  return *s_abort != 0u;
}

// K=512 accumulate. A-fragments: 32 INDEPENDENT system-scope b64 coherent
// loads batched BEFORE the MFMA loop -> one pipelined coherence-point RTT
// (R14's serialized-RTT defect fixed). B: LDS-resident fragment slices.
__device__ __forceinline__ void accK512_sys(fx4* acc, const uint16_t* aq,
                                            const uint16_t* wl, int lane8){
  unsigned long long* a8 = (unsigned long long*)aq;   // 16B-aligned base
  union { unsigned long long q[2]; bfx8 v; } a[16];
  #pragma unroll
  for (int kc = 0; kc < 16; ++kc){
    a[kc].q[0] = __hip_atomic_load(a8 + kc*8 + 0, __ATOMIC_RELAXED, __HIP_MEMORY_SCOPE_SYSTEM);
    a[kc].q[1] = __hip_atomic_load(a8 + kc*8 + 1, __ATOMIC_RELAXED, __HIP_MEMORY_SCOPE_SYSTEM);
  }
  #pragma unroll
  for (int kc = 0; kc < 16; ++kc){
    acc[0] = __builtin_amdgcn_mfma_f32_16x16x32_bf16(a[kc].v, *(const bfx8*)(wl +         kc*512 + lane8), acc[0], 0, 0, 0);
    acc[1] = __builtin_amdgcn_mfma_f32_16x16x32_bf16(a[kc].v, *(const bfx8*)(wl +  8192 + kc*512 + lane8), acc[1], 0, 0, 0);
    acc[2] = __builtin_amdgcn_mfma_f32_16x16x32_bf16(a[kc].v, *(const bfx8*)(wl + 16384 + kc*512 + lane8), acc[2], 0, 0, 0);
    acc[3] = __builtin_amdgcn_mfma_f32_16x16x32_bf16(a[kc].v, *(const bfx8*)(wl + 24576 + kc*512 + lane8), acc[3], 0, 0, 0);
  }
}

// LSTM pointwise; h store = 4 cols packed into one SYSTEM-scope b64 store
// (lanes col%4==0). Write-through to the coherence point.
__device__ __forceinline__ void pointwise(fx4* acc, fx4& creg, int bq, int u,
                                          int col, uint16_t* hout){
  #pragma unroll
  for (int r = 0; r < 4; ++r){
    float iv = sigm(acc[0][r]);
    float fv = sigm(acc[1][r]);
    float gv = tanhf_(acc[2][r]);
    float ov = sigm(acc[3][r]);
    float cn = fv * creg[r] + iv * gv;
    creg[r] = cn;
    unsigned hb = (unsigned)f2bf(ov * tanhf_(cn));
    unsigned p2 = hb | (__shfl_xor(hb, 1) << 16);   // even col: h[c]|h[c+1]
    unsigned hi = __shfl_xor(p2, 2);                // col%4==0: h[c+2]|h[c+3]
    if ((col & 3) == 0){
      unsigned long long v = (unsigned long long)p2 | ((unsigned long long)hi << 32);
      __hip_atomic_store((unsigned long long*)(hout + (size_t)(bq + r)*512 + u), v,
                         __ATOMIC_RELAXED, __HIP_MEMORY_SCOPE_SYSTEM);
    }
  }
}

__global__ void __launch_bounds__(NTHR, 2)
seq2seq_main(const uint16_t* __restrict__ Whh0e, const uint16_t* __restrict__ Wih1e,
             const uint16_t* __restrict__ Whh1e, const uint16_t* __restrict__ Whh0d,
             const uint16_t* __restrict__ Wih1d, const uint16_t* __restrict__ Whh1d,
             const uint16_t* __restrict__ Wy,
             const float* __restrict__ E0e, const float* __restrict__ E0d,
             const float* __restrict__ b1e, const float* __restrict__ b1d,
             const float* __restrict__ wcol0,
             uint16_t* h0buf, uint16_t* h1buf,
             const float* __restrict__ xh, const float* __restrict__ xf,
             const float* __restrict__ y0v,
             const float* __restrict__ encWih0, const float* __restrict__ decWih0,
             const float* __restrict__ projW, const float* __restrict__ projB,
             float* out, unsigned* cntBase)
{
  __shared__ uint4 smem4[8192];                 // 128 KiB static LDS
  __shared__ unsigned s_abort;
  uint16_t* smem = (uint16_t*)smem4;

  const int tid  = threadIdx.x;
  const int lane = tid & 63;
  const int wvi  = tid >> 6;                    // wave in block, 0..7
  const int gh   = wvi >> 2;                    // batch-half within supergroup
  const int wv4  = wvi & 3;                     // M-tile index within half
  const int sg   = blockIdx.x >> 6;             // supergroup (128 batch rows)
  const int k    = blockIdx.x & 63;             // role: 0..31 L0, 32..63 L1
  const bool isL0 = (k < 32);
  const int role = isL0 ? k : k - 32;           // u-slice index, 0..31
  const int col  = lane & 15;
  const int quad = lane >> 4;
  const int g    = (sg << 1) + gh;              // logical 64-row group, 0..3
  const int rowbase = (g << 6) + (wv4 << 4);    // wave's 16-row M-tile base
  const int bq   = rowbase + (quad << 2);
  const int u    = (role << 4) + col;
  const int lane8 = lane << 3;
  unsigned* cntg = cntBase + (size_t)sg * 128;  // 4 counters x 128B / supergroup
  unsigned* abortf = cntBase + 256;             // abort flag (own line, zeroed)
  unsigned* go     = cntBase + 288 + sg*32;     // go word (own line, zeroed)
  const bool leader = (k == 0);
  const int sub  = k >> 4;
  unsigned gen = 0;
  fx4 creg = {0.f, 0.f, 0.f, 0.f};              // c0 (L0) or c1 (L1)
  const float projB_val = projB[0];
  const int hoff = (rowbase + col)*512 + (quad << 3);

  if (tid == 0) s_abort = 0u;

  uint16_t *h0A = h0buf, *h0B = h0buf + BH;
  uint16_t *h1A = h1buf, *h1B = h1buf + BH;

  // ---- stage encoder weight slices into LDS ----
  if (isL0){
    const uint4* s0 = (const uint4*)(Whh0e + (size_t)role*32768);
    for (int i = tid; i < 4096; i += NTHR) smem4[i] = s0[i];
  } else {
    const uint4* s0 = (const uint4*)(Wih1e + (size_t)role*32768);
    const uint4* s1 = (const uint4*)(Whh1e + (size_t)role*32768);
    for (int i = tid; i < 4096; i += NTHR){ smem4[i] = s0[i]; smem4[4096+i] = s1[i]; }
  }

  // ---- hoist per-lane constants into registers ----
  float e0r[4][4], xw[4][8], wc[4], b1r[4], pw8[8];
  if (isL0){
    #pragma unroll
    for (int gg = 0; gg < 4; ++gg){
      #pragma unroll
      for (int r = 0; r < 4; ++r)
        e0r[gg][r] = E0e[(size_t)(bq + r)*2048 + (gg << 9) + u];
      #pragma unroll
      for (int kk = 0; kk < 8; ++kk)
        xw[gg][kk] = encWih0[(size_t)((gg << 9) + u)*24 + kk];
    }
  } else {
    #pragma unroll
    for (int gg = 0; gg < 4; ++gg) b1r[gg] = b1e[(gg << 9) + u];
    if (k < 36){                                // emitY blocks k=32..35
      #pragma unroll
      for (int kk = 0; kk < 8; ++kk) pw8[kk] = projW[lane8 + kk];
    }
  }
  __syncthreads();

  float xve[4][8];                              // enc x prefetch (L0 only)
  auto loadXe = [&](int tt){
    #pragma unroll
    for (int r = 0; r < 4; ++r){
      const float* xr = xh + ((size_t)(bq + r)*288 + tt)*8;
      #pragma unroll
      for (int kk = 0; kk < 8; ++kk) xve[r][kk] = xr[kk];
    }
  };

  auto encCompute = [&](const uint16_t* h0c, uint16_t* h0n){
    fx4 acc[4];
    #pragma unroll
    for (int gg = 0; gg < 4; ++gg)
      #pragma unroll
      for (int r = 0; r < 4; ++r) acc[gg][r] = e0r[gg][r];
    accK512_sys(acc, h0c + hoff, smem, lane8);
    #pragma unroll
    for (int gg = 0; gg < 4; ++gg)
      #pragma unroll
      for (int kk = 0; kk < 8; ++kk){
        float w = xw[gg][kk];
        #pragma unroll
        for (int r = 0; r < 4; ++r) acc[gg][r] += w * xve[r][kk];
      }
    pointwise(acc, creg, bq, u, col, h0n);
  };

  // emitY: blocks k=32..35; per half, wave wv4 covers 4 rows. System-scope
  // coherent h1 reads (no inv in this design); single-writer out stores.
  auto emitY = [&](const uint16_t* h1cur, int tt){
    int rb = (g << 6) + ((k - 32) << 4) + (wv4 << 2);
    #pragma unroll 1
    for (int j = 0; j < 4; ++j){
      int b = rb + j;
      unsigned long long* hr8 = (unsigned long long*)(h1cur + (size_t)b*512 + lane8);
      union { unsigned long long q[2]; uint16_t s[8]; } hh;
      hh.q[0] = __hip_atomic_load(hr8 + 0, __ATOMIC_RELAXED, __HIP_MEMORY_SCOPE_SYSTEM);
      hh.q[1] = __hip_atomic_load(hr8 + 1, __ATOMIC_RELAXED, __HIP_MEMORY_SCOPE_SYSTEM);
      float part = 0.f;
      #pragma unroll
      for (int kk = 0; kk < 8; ++kk) part += bf2f(hh.s[kk]) * pw8[kk];
      #pragma unroll
      for (int off = 32; off > 0; off >>= 1) part += __shfl_down(part, off);
      if (lane == 0) out[(size_t)b*288 + tt] = part + projB_val;
    }
  };

  // ---- prologue: enc L0 t=0 (h_{-1}=0 via memset) ----
  if (isL0){
    loadXe(0);
    encCompute(h0A, h0B);
    loadXe(1);                                  // prefetch x_1, overlaps barrier
  }
  if (groupbar(cntg, sub, ++gen, go, leader, abortf, &s_abort)) return;
  { uint16_t* t_ = h0A; h0A = h0B; h0B = t_; }   // h0A = h0_0

  // ---- encoder: 1 barrier/step; L1_t || L0_{t+1} ----
  #pragma unroll 1
  for (int t = 0; t < 288; ++t){
    if (isL0){
      if (t < 287){
        encCompute(h0A, h0B);                   // step t+1 (uses xve = x_{t+1})
        if (t < 286) loadXe(t + 2);             // prefetch x_{t+2} before bar
      }
    } else {
      fx4 acc[4];
      #pragma unroll
      for (int gg = 0; gg < 4; ++gg)
        #pragma unroll
        for (int r = 0; r < 4; ++r) acc[gg][r] = b1r[gg];
      accK512_sys(acc, h0A + hoff, smem, lane8);            // Wih1e * h0_t
      accK512_sys(acc, h1A + hoff, smem + 32768, lane8);    // Whh1e * h1_{t-1}
      pointwise(acc, creg, bq, u, col, h1B);
    }
    if (groupbar(cntg, sub, ++gen, go, leader, abortf, &s_abort)) return;
    { uint16_t* t_ = h1A; h1A = h1B; h1B = t_; }
    if (t < 287){ uint16_t* t_ = h0A; h0A = h0B; h0B = t_; }
  }
  // h0A = h0_287, h1A = h1_287; c continues into decoder.

  // ---- restage decoder weights + regs (block-local) ----
  float xvd[4][6];                              // dec x prefetch (L0 only)
  auto loadXd = [&](int tt){
    #pragma unroll
    for (int r = 0; r < 4; ++r){
      const float* xr = xf + ((size_t)(bq + r)*288 + tt)*6;
      #pragma unroll
      for (int kk = 0; kk < 6; ++kk) xvd[r][kk] = xr[kk];
    }
  };
  if (isL0){
    const uint4* s0 = (const uint4*)(Whh0d + (size_t)role*32768);
    const uint4* s1 = (const uint4*)(Wy    + (size_t)role*32768);
    for (int i = tid; i < 4096; i += NTHR){ smem4[i] = s0[i]; smem4[4096+i] = s1[i]; }
    #pragma unroll
    for (int gg = 0; gg < 4; ++gg){
      #pragma unroll
      for (int r = 0; r < 4; ++r)
        e0r[gg][r] = E0d[(size_t)(bq + r)*2048 + (gg << 9) + u];
      #pragma unroll
      for (int kk = 0; kk < 6; ++kk)
        xw[gg][kk] = decWih0[(size_t)((gg << 9) + u)*23 + 1 + kk];
      wc[gg] = wcol0[(gg << 9) + u];
    }
    loadXd(0);
  } else {
    const uint4* s0 = (const uint4*)(Wih1d + (size_t)role*32768);
    const uint4* s1 = (const uint4*)(Whh1d + (size_t)role*32768);
    for (int i = tid; i < 4096; i += NTHR){ smem4[i] = s0[i]; smem4[4096+i] = s1[i]; }
    #pragma unroll
    for (int gg = 0; gg < 4; ++gg) b1r[gg] = b1d[(gg << 9) + u];
  }
  __syncthreads();

  auto decCompute = [&](int tt, const uint16_t* h0c, const uint16_t* h1c,
                        uint16_t* h0n){
    fx4 acc[4];
    #pragma unroll
    for (int gg = 0; gg < 4; ++gg)
      #pragma unroll
      for (int r = 0; r < 4; ++r) acc[gg][r] = e0r[gg][r];
    accK512_sys(acc, h0c + hoff, smem, lane8);              // Whh0d
    if (tt > 0)
      accK512_sys(acc, h1c + hoff, smem + 32768, lane8);    // Wy
    float s[4];
    #pragma unroll
    for (int r = 0; r < 4; ++r) s[r] = (tt == 0) ? y0v[bq + r] : projB_val;
    #pragma unroll
    for (int gg = 0; gg < 4; ++gg){
      #pragma unroll
      for (int r = 0; r < 4; ++r) acc[gg][r] += wc[gg] * s[r];
      #pragma unroll
      for (int kk = 0; kk < 6; ++kk){
        float w = xw[gg][kk];
        #pragma unroll
        for (int r = 0; r < 4; ++r) acc[gg][r] += w * xvd[r][kk];
      }
    }
    pointwise(acc, creg, bq, u, col, h0n);
  };

  // ---- decoder: 2 barriers/step (R15 structure) ----
  #pragma unroll 1
  for (int t = 0; t < 288; ++t){
    if (isL0){
      decCompute(t, h0A, h1A, h0B);             // uses xvd = x_t
      if (t < 287) loadXd(t + 1);               // prefetch x_{t+1} before bar
    } else if (k < 36 && t > 0){
      emitY(h1A, t - 1);
    }
    if (groupbar(cntg, sub, ++gen, go, leader, abortf, &s_abort)) return;
    if (!isL0){
      fx4 acc[4];
      #pragma unroll
      for (int gg = 0; gg < 4; ++gg)
        #pragma unroll
        for (int r = 0; r < 4; ++r) acc[gg][r] = b1r[gg];
      accK512_sys(acc, h1A + hoff, smem + 32768, lane8);    // Whh1d * h1_{t-1}
      accK512_sys(acc, h0B + hoff, smem, lane8);            // Wih1d * h0_t
      pointwise(acc, creg, bq, u, col, h1B);
    }
    if (groupbar(cntg, sub, ++gen, go, leader, abortf, &s_abort)) return;
    { uint16_t* t_ = h0A; h0A = h0B; h0B = t_; }
    { uint16_t* t_ = h1A; h1A = h1B; h1B = t_; }
  }

  // final y_287 (h1A = h1_287, published by last barrier)
  if (!isL0 && k < 36) emitY(h1A, 287);
}

// ---------------- prep: frag-ordered bf16 weights (+Wy), emb+bias folds ----
#define PREP_S 1048576
#define PREP_TOTAL (7*PREP_S + 1048576 + 6144)

__global__ void __launch_bounds__(256)
prep_kernel(const float* __restrict__ encWih0, const float* __restrict__ encWhh0,
            const float* __restrict__ encWih1, const float* __restrict__ encWhh1,
            const float* __restrict__ decWih0, const float* __restrict__ decWhh0,
            const float* __restrict__ decWih1, const float* __restrict__ decWhh1,
            const float* __restrict__ encbih0, const float* __restrict__ encbhh0,
            const float* __restrict__ encbih1, const float* __restrict__ encbhh1,
            const float* __restrict__ decbih0, const float* __restrict__ decbhh0,
            const float* __restrict__ decbih1, const float* __restrict__ decbhh1,
            const float* __restrict__ projW, const float* __restrict__ emb,
            const int* __restrict__ turb,
            uint16_t* Whh0e, uint16_t* Wih1e, uint16_t* Whh1e,
            uint16_t* Whh0d, uint16_t* Wih1d, uint16_t* Whh1d, uint16_t* Wyp,
            float* E0e, float* E0d, float* b1e, float* b1d, float* wcol0)
{
  int i = blockIdx.x*256 + threadIdx.x;
  if (i >= PREP_TOTAL) return;
  if (i < 7*PREP_S){
    // fragment reorder: dest = role*32768 + gate*8192 + kc*512 + lane*8 + j
    // value = W[gate*512 + role*16 + (lane&15)][kc*32 + (lane>>4)*8 + j]
    int w = i >> 20, r = i & (PREP_S - 1);
    int role = r >> 15;
    int rem  = r & 32767;
    int gate = rem >> 13;
    int kc   = (rem >> 9) & 15;
    int ln   = (rem >> 3) & 63;
    int j    = rem & 7;
    int c = ln & 15, q = ln >> 4;
    int row  = (gate << 9) + (role << 4) + c;
    int colk = (kc << 5) + (q << 3) + j;
    float v;
    if (w == 6){
      v = decWih0[(size_t)row*23] * projW[colk];     // Wy = wcol0 (x) projW
    } else {
      const float* src = (w==0)?encWhh0:(w==1)?encWih1:(w==2)?encWhh1:
                         (w==3)?decWhh0:(w==4)?decWih1:decWhh1;
      v = src[(size_t)row*512 + colk];
    }
    uint16_t* dst = (w==0)?Whh0e:(w==1)?Wih1e:(w==2)?Whh1e:
                    (w==3)?Whh0d:(w==4)?Wih1d:(w==5)?Whh1d:Wyp;
    dst[r] = f2bf(v);
  } else if (i < 7*PREP_S + 524288){
    int r = i - 7*PREP_S; int b = r >> 11, j = r & 2047;
    float s = encbih0[j] + encbhh0[j];
    const float* e = emb + (size_t)turb[b]*16;
    const float* wr = encWih0 + (size_t)j*24 + 8;
    #pragma unroll
    for (int m = 0; m < 16; ++m) s += e[m]*wr[m];
    E0e[r] = s;
  } else if (i < 7*PREP_S + 1048576){
    int r = i - 7*PREP_S - 524288; int b = r >> 11, j = r & 2047;
    float s = decbih0[j] + decbhh0[j];
    const float* e = emb + (size_t)turb[b]*16;
    const float* wr = decWih0 + (size_t)j*23 + 7;
    #pragma unroll
    for (int m = 0; m < 16; ++m) s += e[m]*wr[m];
    E0d[r] = s;
  } else {
    int r = i - 7*PREP_S - 1048576;
    if (r < 2048)      b1e[r] = encbih1[r] + encbhh1[r];
    else if (r < 4096){ int j = r - 2048; b1d[j] = decbih1[j] + decbhh1[j]; }
    else              { int j = r - 4096; wcol0[j] = decWih0[(size_t)j*23]; }
  }
}

// ---------------------------------------------------------------------------
extern "C" void kernel_launch(void* const* d_in, const int* in_sizes, int n_in,
                              void* d_out, int out_size, void* d_ws, size_t ws_size,
                              hipStream_t stream)
{
  const float* xh      = (const float*)d_in[0];
  const float* xf      = (const float*)d_in[1];
  const float* y0v     = (const float*)d_in[2];
  const int*   turb    = (const int*)d_in[3];
  const float* emb     = (const float*)d_in[5];
  const float* encWih0 = (const float*)d_in[6];
  const float* encWhh0 = (const float*)d_in[7];
  const float* encbih0 = (const float*)d_in[8];
  const float* encbhh0 = (const float*)d_in[9];
  const float* encWih1 = (const float*)d_in[10];
  const float* encWhh1 = (const float*)d_in[11];
  const float* encbih1 = (const float*)d_in[12];
  const float* encbhh1 = (const float*)d_in[13];
  const float* decWih0 = (const float*)d_in[14];
  const float* decWhh0 = (const float*)d_in[15];
  const float* decbih0 = (const float*)d_in[16];
  const float* decbhh0 = (const float*)d_in[17];
  const float* decWih1 = (const float*)d_in[18];
  const float* decWhh1 = (const float*)d_in[19];
  const float* decbih1 = (const float*)d_in[20];
  const float* decbhh1 = (const float*)d_in[21];
  const float* projW   = (const float*)d_in[22];
  const float* projB   = (const float*)d_in[23];
  float* out = (float*)d_out;

  char* ws = (char*)d_ws;
  constexpr size_t SZW = (size_t)2048*512*2;        // 2 MiB per matrix
  constexpr size_t OFF_Whh0e = 0;
  constexpr size_t OFF_Wih1e = SZW;
  constexpr size_t OFF_Whh1e = 2*SZW;
  constexpr size_t OFF_Whh0d = 3*SZW;
  constexpr size_t OFF_Wih1d = 4*SZW;
  constexpr size_t OFF_Whh1d = 5*SZW;
  constexpr size_t OFF_Wy    = 6*SZW;
  constexpr size_t OFF_E0e   = 7*SZW;
  constexpr size_t OFF_E0d   = OFF_E0e + 2097152;
  constexpr size_t OFF_b1e   = OFF_E0d + 2097152;
  constexpr size_t OFF_b1d   = OFF_b1e + 8192;
  constexpr size_t OFF_wcol0 = OFF_b1d + 8192;
  constexpr size_t OFF_h0    = OFF_wcol0 + 8192;
  constexpr size_t OFF_h1    = OFF_h0 + 524288;
  constexpr size_t OFF_cnt   = OFF_h1 + 524288;
  constexpr size_t ZERO_BYTES = 2*524288 + 2048;    // h0,h1 ping-pong + counters+go+abort

  uint16_t* Whh0e = (uint16_t*)(ws + OFF_Whh0e);
  uint16_t* Wih1e = (uint16_t*)(ws + OFF_Wih1e);
  uint16_t* Whh1e = (uint16_t*)(ws + OFF_Whh1e);
  uint16_t* Whh0d = (uint16_t*)(ws + OFF_Whh0d);
  uint16_t* Wih1d = (uint16_t*)(ws + OFF_Wih1d);
  uint16_t* Whh1d = (uint16_t*)(ws + OFF_Whh1d);
  uint16_t* Wyp   = (uint16_t*)(ws + OFF_Wy);
  float* E0e   = (float*)(ws + OFF_E0e);
  float* E0d   = (float*)(ws + OFF_E0d);
  float* b1e   = (float*)(ws + OFF_b1e);
  float* b1d   = (float*)(ws + OFF_b1d);
  float* wcol0 = (float*)(ws + OFF_wcol0);
  uint16_t* h0p = (uint16_t*)(ws + OFF_h0);
  uint16_t* h1p = (uint16_t*)(ws + OFF_h1);
  unsigned* cntp = (unsigned*)(ws + OFF_cnt);

  hipMemsetAsync(ws + OFF_h0, 0, ZERO_BYTES, stream);

  prep_kernel<<<dim3((PREP_TOTAL + 255)/256), dim3(256), 0, stream>>>(
      encWih0, encWhh0, encWih1, encWhh1, decWih0, decWhh0, decWih1, decWhh1,
      encbih0, encbhh0, encbih1, encbhh1, decbih0, decbhh0, decbih1, decbhh1,
      projW, emb, turb,
      Whh0e, Wih1e, Whh1e, Whh0d, Wih1d, Whh1d, Wyp,
      E0e, E0d, b1e, b1d, wcol0);

  // Plain launch (proven R11/R14/R15/R18). 128 blocks on 256 CUs @ 1 block/CU
  // -> co-residency with 2x slack; barrier spin is abort-guarded.
  seq2seq_main<<<dim3(NBLK), dim3(NTHR), 0, stream>>>(
      Whh0e, Wih1e, Whh1e, Whh0d, Wih1d, Whh1d, Wyp,
      E0e, E0d, b1e, b1d, wcol0,
      h0p, h1p, xh, xf, y0v,
      encWih0, decWih0, projW, projB,
      out, cntp);
}

// Round 13
// 9794.382 us; speedup vs baseline: 1.7044x; 1.7044x over previous
//
#include <hip/hip_runtime.h>
#include <stdint.h>

// ---------------------------------------------------------------------------
// R20 = R15 (9.95ms, session best) + leader poll via system-scope LOADS.
//   Exhaustive mapping: R15 inv-barrier/leader-go 9.95 | R18 +data-path 10.07
//   | R17 directed 10.4 | R16 leaderless 10.5 | R11 wbl2+inv 12.26 | R14
//   uncached-serial 15.85 | R19 uncached-batched 16.69. Conclusions:
//   (1) L2-cached h reads + acquire-inv strictly beat coherence-point reads
//       (L2 provides cross-block sharing; FETCH_SIZE proves system loads
//       re-pull per block). (2) Sync topology variants are within noise ->
//       tau ~= 11.5us/phase is fabric-RTT + max-of-64 skew, not topology.
//   The one remaining clean lever: leader detect used 4 SEQUENTIALLY-retired
//   agent RMWs on the same lines the 64 arrival RMWs are landing on (RMWs to
//   a line serialize at the MALL). Swap to 4 pipelined system-scope loads
//   (R16-proven to observe these counters) -> detect ~1 RTT, no contention.
//   Everything else byte-identical to R15:
//   - h stores: 2-col packed system-scope atomic dword (write-through; no
//     dirty h lines in L2 -> no wbl2 needed; acked before vmcnt(0) drain).
//   - h reads: plain b128, L2-shared, refreshed by acquire-inv at barrier exit.
//   - LDS-resident frag-ordered weights; E0/xw/b1/projW folds in registers.
//   - 2 supergroups x 64 roles, 128 blk x 512 thr, Wy rank-1 y-feedback,
//     emitY single-writer, abort-guarded spins, plain launch.
// ---------------------------------------------------------------------------

typedef __attribute__((ext_vector_type(8))) short bfx8;   // 8 bf16 (4 VGPRs)
typedef __attribute__((ext_vector_type(4))) float fx4;

#define NBLK 128
#define NTHR 512
#define BH   (256*512)

__device__ __forceinline__ unsigned short f2bf(float f){
  unsigned u = __float_as_uint(f);
  u += 0x7FFFu + ((u >> 16) & 1u);          // RNE
  return (unsigned short)(u >> 16);
}
__device__ __forceinline__ float bf2f(unsigned short b){
  return __uint_as_float(((unsigned)b) << 16);
}
__device__ __forceinline__ float sigm(float x){ return 1.0f/(1.0f + __expf(-x)); }
__device__ __forceinline__ float tanhf_(float x){
  x = fminf(12.0f, fmaxf(-12.0f, x));
  float e = __expf(2.0f*x);
  return (e - 1.0f)/(e + 1.0f);
}

// 64-block supergroup barrier, leader/go structure (R15) with load-based
// leader detect.
__device__ __forceinline__ bool groupbar(unsigned* cntg, int sub, unsigned gen,
                                         unsigned* go, bool leader,
                                         unsigned* abortf, volatile unsigned* s_abort){
  __syncthreads();
  if (threadIdx.x == 0){
    __hip_atomic_fetch_add(cntg + sub*32, 1u, __ATOMIC_RELAXED, __HIP_MEMORY_SCOPE_AGENT);
    const unsigned target = gen*16u;
    unsigned spins = 0;
    if (leader){
      for (;;){
        unsigned v0 = __hip_atomic_load(cntg +  0, __ATOMIC_RELAXED, __HIP_MEMORY_SCOPE_SYSTEM);
        unsigned v1 = __hip_atomic_load(cntg + 32, __ATOMIC_RELAXED, __HIP_MEMORY_SCOPE_SYSTEM);
        unsigned v2 = __hip_atomic_load(cntg + 64, __ATOMIC_RELAXED, __HIP_MEMORY_SCOPE_SYSTEM);
        unsigned v3 = __hip_atomic_load(cntg + 96, __ATOMIC_RELAXED, __HIP_MEMORY_SCOPE_SYSTEM);
        if (v0 >= target && v1 >= target && v2 >= target && v3 >= target) break;
        if (((++spins) & 1023u) == 0u){
          if (__hip_atomic_load(abortf, __ATOMIC_RELAXED, __HIP_MEMORY_SCOPE_AGENT) != 0u){
            *s_abort = 1u; break;
          }
          if (spins > (1u << 20)){
            __hip_atomic_store(abortf, 1u, __ATOMIC_RELAXED, __HIP_MEMORY_SCOPE_AGENT);
            *s_abort = 1u; break;
          }
        }
        __builtin_amdgcn_s_sleep(2);
      }
      __hip_atomic_store(go, gen, __ATOMIC_RELAXED, __HIP_MEMORY_SCOPE_SYSTEM);
    } else {
      while (__hip_atomic_load(go, __ATOMIC_RELAXED, __HIP_MEMORY_SCOPE_SYSTEM) < gen){
        if (((++spins) & 1023u) == 0u){
          if (__hip_atomic_load(abortf, __ATOMIC_RELAXED, __HIP_MEMORY_SCOPE_AGENT) != 0u){
            *s_abort = 1u; break;
          }
          if (spins > (1u << 20)){
            __hip_atomic_store(abortf, 1u, __ATOMIC_RELAXED, __HIP_MEMORY_SCOPE_AGENT);
            *s_abort = 1u; break;
          }
        }
        __builtin_amdgcn_s_sleep(2);
      }
    }
    (void)__hip_atomic_load(cntg, __ATOMIC_ACQUIRE, __HIP_MEMORY_SCOPE_AGENT);  // buffer_inv
  }
  __syncthreads();
  return *s_abort != 0u;
}

// K=512 accumulate: A rows from global h via PLAIN b128 loads (L2-cached,
// shared across the XCD's blocks; fresh after the barrier's buffer_inv);
// B = 4 gate-slices from LDS fragment layout ([gate][kc][lane][8]).
__device__ __forceinline__ void accK512_lds(fx4* acc, const uint16_t* aq,
                                            const uint16_t* wl, int lane8){
  #pragma unroll
  for (int kc = 0; kc < 16; ++kc){
    bfx8 af = *(const bfx8*)(aq + kc*32);
    acc[0] = __builtin_amdgcn_mfma_f32_16x16x32_bf16(af, *(const bfx8*)(wl +         kc*512 + lane8), acc[0], 0, 0, 0);
    acc[1] = __builtin_amdgcn_mfma_f32_16x16x32_bf16(af, *(const bfx8*)(wl +  8192 + kc*512 + lane8), acc[1], 0, 0, 0);
    acc[2] = __builtin_amdgcn_mfma_f32_16x16x32_bf16(af, *(const bfx8*)(wl + 16384 + kc*512 + lane8), acc[2], 0, 0, 0);
    acc[3] = __builtin_amdgcn_mfma_f32_16x16x32_bf16(af, *(const bfx8*)(wl + 24576 + kc*512 + lane8), acc[3], 0, 0, 0);
  }
}

// LSTM pointwise; h store = packed 2-col SYSTEM-scope atomic dword (write-
// through to the coherence point; acked before vmcnt(0) drain).
__device__ __forceinline__ void pointwise(fx4* acc, fx4& creg, int bq, int u,
                                          int col, uint16_t* hout){
  #pragma unroll
  for (int r = 0; r < 4; ++r){
    float iv = sigm(acc[0][r]);
    float fv = sigm(acc[1][r]);
    float gv = tanhf_(acc[2][r]);
    float ov = sigm(acc[3][r]);
    float cn = fv * creg[r] + iv * gv;
    creg[r] = cn;
    unsigned hb = (unsigned)f2bf(ov * tanhf_(cn));
    unsigned nb = __shfl_xor(hb, 1);
    if ((col & 1) == 0){
      __hip_atomic_store((unsigned*)(hout + (size_t)(bq + r)*512 + u), hb | (nb << 16),
                         __ATOMIC_RELAXED, __HIP_MEMORY_SCOPE_SYSTEM);
    }
  }
}

__global__ void __launch_bounds__(NTHR, 2)
seq2seq_main(const uint16_t* __restrict__ Whh0e, const uint16_t* __restrict__ Wih1e,
             const uint16_t* __restrict__ Whh1e, const uint16_t* __restrict__ Whh0d,
             const uint16_t* __restrict__ Wih1d, const uint16_t* __restrict__ Whh1d,
             const uint16_t* __restrict__ Wy,
             const float* __restrict__ E0e, const float* __restrict__ E0d,
             const float* __restrict__ b1e, const float* __restrict__ b1d,
             const float* __restrict__ wcol0,
             uint16_t* h0buf, uint16_t* h1buf,
             const float* __restrict__ xh, const float* __restrict__ xf,
             const float* __restrict__ y0v,
             const float* __restrict__ encWih0, const float* __restrict__ decWih0,
             const float* __restrict__ projW, const float* __restrict__ projB,
             float* out, unsigned* cntBase)
{
  __shared__ uint4 smem4[8192];                 // 128 KiB static LDS
  __shared__ unsigned s_abort;
  uint16_t* smem = (uint16_t*)smem4;

  const int tid  = threadIdx.x;
  const int lane = tid & 63;
  const int wvi  = tid >> 6;                    // wave in block, 0..7
  const int gh   = wvi >> 2;                    // batch-half within supergroup
  const int wv4  = wvi & 3;                     // M-tile index within half
  const int sg   = blockIdx.x >> 6;             // supergroup (128 batch rows)
  const int k    = blockIdx.x & 63;             // role: 0..31 L0, 32..63 L1
  const bool isL0 = (k < 32);
  const int role = isL0 ? k : k - 32;           // u-slice index, 0..31
  const int col  = lane & 15;
  const int quad = lane >> 4;
  const int g    = (sg << 1) + gh;              // logical 64-row group, 0..3
  const int rowbase = (g << 6) + (wv4 << 4);    // wave's 16-row M-tile base
  const int bq   = rowbase + (quad << 2);
  const int u    = (role << 4) + col;
  const int lane8 = lane << 3;
  unsigned* cntg = cntBase + (size_t)sg * 128;  // 4 counters x 128B / supergroup
  unsigned* abortf = cntBase + 256;             // abort flag (own line, zeroed)
  unsigned* go     = cntBase + 288 + sg*32;     // go word (own line, zeroed)
  const bool leader = (k == 0);
  const int sub  = k >> 4;
  unsigned gen = 0;
  fx4 creg = {0.f, 0.f, 0.f, 0.f};              // c0 (L0) or c1 (L1)
  const float projB_val = projB[0];

  if (tid == 0) s_abort = 0u;

  uint16_t *h0A = h0buf, *h0B = h0buf + BH;
  uint16_t *h1A = h1buf, *h1B = h1buf + BH;

  // ---- stage encoder weight slices into LDS ----
  if (isL0){
    const uint4* s0 = (const uint4*)(Whh0e + (size_t)role*32768);
    for (int i = tid; i < 4096; i += NTHR) smem4[i] = s0[i];
  } else {
    const uint4* s0 = (const uint4*)(Wih1e + (size_t)role*32768);
    const uint4* s1 = (const uint4*)(Whh1e + (size_t)role*32768);
    for (int i = tid; i < 4096; i += NTHR){ smem4[i] = s0[i]; smem4[4096+i] = s1[i]; }
  }

  // ---- hoist per-lane constants into registers ----
  float e0r[4][4], xw[4][8], wc[4], b1r[4], pw8[8];
  if (isL0){
    #pragma unroll
    for (int gg = 0; gg < 4; ++gg){
      #pragma unroll
      for (int r = 0; r < 4; ++r)
        e0r[gg][r] = E0e[(size_t)(bq + r)*2048 + (gg << 9) + u];
      #pragma unroll
      for (int kk = 0; kk < 8; ++kk)
        xw[gg][kk] = encWih0[(size_t)((gg << 9) + u)*24 + kk];
    }
  } else {
    #pragma unroll
    for (int gg = 0; gg < 4; ++gg) b1r[gg] = b1e[(gg << 9) + u];
    if (k < 36){                                // emitY blocks k=32..35
      #pragma unroll
      for (int kk = 0; kk < 8; ++kk) pw8[kk] = projW[lane8 + kk];
    }
  }
  __syncthreads();

  auto encCompute = [&](int tt, const uint16_t* h0c, uint16_t* h0n){
    fx4 acc[4];
    #pragma unroll
    for (int gg = 0; gg < 4; ++gg)
      #pragma unroll
      for (int r = 0; r < 4; ++r) acc[gg][r] = e0r[gg][r];
    float xv[4][8];
    #pragma unroll
    for (int r = 0; r < 4; ++r){
      const float* xr = xh + ((size_t)(bq + r)*288 + tt)*8;
      #pragma unroll
      for (int kk = 0; kk < 8; ++kk) xv[r][kk] = xr[kk];
    }
    accK512_lds(acc, h0c + (size_t)(rowbase + col)*512 + (quad << 3), smem, lane8);
    #pragma unroll
    for (int gg = 0; gg < 4; ++gg)
      #pragma unroll
      for (int kk = 0; kk < 8; ++kk){
        float w = xw[gg][kk];
        #pragma unroll
        for (int r = 0; r < 4; ++r) acc[gg][r] += w * xv[r][kk];
      }
    pointwise(acc, creg, bq, u, col, h0n);
  };

  // emitY: blocks k=32..35; per half, wave wv4 covers 4 rows. Plain loads
  // (fresh after barrier inv); single-writer out stores.
  auto emitY = [&](const uint16_t* h1cur, int tt){
    int rb = (g << 6) + ((k - 32) << 4) + (wv4 << 2);
    #pragma unroll 1
    for (int j = 0; j < 4; ++j){
      int b = rb + j;
      const uint16_t* hr = h1cur + (size_t)b*512 + lane8;
      float part = 0.f;
      #pragma unroll
      for (int kk = 0; kk < 8; ++kk) part += bf2f(hr[kk]) * pw8[kk];
      #pragma unroll
      for (int off = 32; off > 0; off >>= 1) part += __shfl_down(part, off);
      if (lane == 0) out[(size_t)b*288 + tt] = part + projB_val;
    }
  };

  // ---- prologue: enc L0 t=0 (h_{-1}=0 via memset) ----
  if (isL0) encCompute(0, h0A, h0B);
  if (groupbar(cntg, sub, ++gen, go, leader, abortf, &s_abort)) return;
  { uint16_t* t_ = h0A; h0A = h0B; h0B = t_; }   // h0A = h0_0

  // ---- encoder: 1 barrier/step; L1_t || L0_{t+1} ----
  #pragma unroll 1
  for (int t = 0; t < 288; ++t){
    if (isL0){
      if (t < 287) encCompute(t + 1, h0A, h0B);
    } else {
      fx4 acc[4];
      #pragma unroll
      for (int gg = 0; gg < 4; ++gg)
        #pragma unroll
        for (int r = 0; r < 4; ++r) acc[gg][r] = b1r[gg];
      accK512_lds(acc, h0A + (size_t)(rowbase + col)*512 + (quad << 3), smem, lane8);          // Wih1e
      accK512_lds(acc, h1A + (size_t)(rowbase + col)*512 + (quad << 3), smem + 32768, lane8);  // Whh1e
      pointwise(acc, creg, bq, u, col, h1B);
    }
    if (groupbar(cntg, sub, ++gen, go, leader, abortf, &s_abort)) return;
    { uint16_t* t_ = h1A; h1A = h1B; h1B = t_; }
    if (t < 287){ uint16_t* t_ = h0A; h0A = h0B; h0B = t_; }
  }
  // h0A = h0_287, h1A = h1_287; c continues into decoder.

  // ---- restage decoder weights + regs (block-local) ----
  if (isL0){
    const uint4* s0 = (const uint4*)(Whh0d + (size_t)role*32768);
    const uint4* s1 = (const uint4*)(Wy    + (size_t)role*32768);
    for (int i = tid; i < 4096; i += NTHR){ smem4[i] = s0[i]; smem4[4096+i] = s1[i]; }
    #pragma unroll
    for (int gg = 0; gg < 4; ++gg){
      #pragma unroll
      for (int r = 0; r < 4; ++r)
        e0r[gg][r] = E0d[(size_t)(bq + r)*2048 + (gg << 9) + u];
      #pragma unroll
      for (int kk = 0; kk < 6; ++kk)
        xw[gg][kk] = decWih0[(size_t)((gg << 9) + u)*23 + 1 + kk];
      wc[gg] = wcol0[(gg << 9) + u];
    }
  } else {
    const uint4* s0 = (const uint4*)(Wih1d + (size_t)role*32768);
    const uint4* s1 = (const uint4*)(Whh1d + (size_t)role*32768);
    for (int i = tid; i < 4096; i += NTHR){ smem4[i] = s0[i]; smem4[4096+i] = s1[i]; }
    #pragma unroll
    for (int gg = 0; gg < 4; ++gg) b1r[gg] = b1d[(gg << 9) + u];
  }
  __syncthreads();

  auto decCompute = [&](int tt, const uint16_t* h0c, const uint16_t* h1c,
                        uint16_t* h0n){
    fx4 acc[4];
    #pragma unroll
    for (int gg = 0; gg < 4; ++gg)
      #pragma unroll
      for (int r = 0; r < 4; ++r) acc[gg][r] = e0r[gg][r];
    accK512_lds(acc, h0c + (size_t)(rowbase + col)*512 + (quad << 3), smem, lane8);           // Whh0d
    if (tt > 0)
      accK512_lds(acc, h1c + (size_t)(rowbase + col)*512 + (quad << 3), smem + 32768, lane8); // Wy
    float s[4];
    #pragma unroll
    for (int r = 0; r < 4; ++r) s[r] = (tt == 0) ? y0v[bq + r] : projB_val;
    float xv[4][6];
    #pragma unroll
    for (int r = 0; r < 4; ++r){
      const float* xr = xf + ((size_t)(bq + r)*288 + tt)*6;
      #pragma unroll
      for (int kk = 0; kk < 6; ++kk) xv[r][kk] = xr[kk];
    }
    #pragma unroll
    for (int gg = 0; gg < 4; ++gg){
      #pragma unroll
      for (int r = 0; r < 4; ++r) acc[gg][r] += wc[gg] * s[r];
      #pragma unroll
      for (int kk = 0; kk < 6; ++kk){
        float w = xw[gg][kk];
        #pragma unroll
        for (int r = 0; r < 4; ++r) acc[gg][r] += w * xv[r][kk];
      }
    }
    pointwise(acc, creg, bq, u, col, h0n);
  };

  // ---- decoder: 2 barriers/step (R15 structure) ----
  #pragma unroll 1
  for (int t = 0; t < 288; ++t){
    if (isL0){
      decCompute(t, h0A, h1A, h0B);
    } else if (k < 36 && t > 0){
      emitY(h1A, t - 1);
    }
    if (groupbar(cntg, sub, ++gen, go, leader, abortf, &s_abort)) return;
    if (!isL0){
      fx4 acc[4];
      #pragma unroll
      for (int gg = 0; gg < 4; ++gg)
        #pragma unroll
        for (int r = 0; r < 4; ++r) acc[gg][r] = b1r[gg];
      accK512_lds(acc, h1A + (size_t)(rowbase + col)*512 + (quad << 3), smem + 32768, lane8); // Whh1d
      accK512_lds(acc, h0B + (size_t)(rowbase + col)*512 + (quad << 3), smem, lane8);         // Wih1d
      pointwise(acc, creg, bq, u, col, h1B);
    }
    if (groupbar(cntg, sub, ++gen, go, leader, abortf, &s_abort)) return;
    { uint16_t* t_ = h0A; h0A = h0B; h0B = t_; }
    { uint16_t* t_ = h1A; h1A = h1B; h1B = t_; }
  }

  // final y_287 (h1A = h1_287, published by last barrier)
  if (!isL0 && k < 36) emitY(h1A, 287);
}

// ---------------- prep: frag-ordered bf16 weights (+Wy), emb+bias folds ----
#define PREP_S 1048576
#define PREP_TOTAL (7*PREP_S + 1048576 + 6144)

__global__ void __launch_bounds__(256)
prep_kernel(const float* __restrict__ encWih0, const float* __restrict__ encWhh0,
            const float* __restrict__ encWih1, const float* __restrict__ encWhh1,
            const float* __restrict__ decWih0, const float* __restrict__ decWhh0,
            const float* __restrict__ decWih1, const float* __restrict__ decWhh1,
            const float* __restrict__ encbih0, const float* __restrict__ encbhh0,
            const float* __restrict__ encbih1, const float* __restrict__ encbhh1,
            const float* __restrict__ decbih0, const float* __restrict__ decbhh0,
            const float* __restrict__ decbih1, const float* __restrict__ decbhh1,
            const float* __restrict__ projW, const float* __restrict__ emb,
            const int* __restrict__ turb,
            uint16_t* Whh0e, uint16_t* Wih1e, uint16_t* Whh1e,
            uint16_t* Whh0d, uint16_t* Wih1d, uint16_t* Whh1d, uint16_t* Wyp,
            float* E0e, float* E0d, float* b1e, float* b1d, float* wcol0)
{
  int i = blockIdx.x*256 + threadIdx.x;
  if (i >= PREP_TOTAL) return;
  if (i < 7*PREP_S){
    // fragment reorder: dest = role*32768 + gate*8192 + kc*512 + lane*8 + j
    // value = W[gate*512 + role*16 + (lane&15)][kc*32 + (lane>>4)*8 + j]
    int w = i >> 20, r = i & (PREP_S - 1);
    int role = r >> 15;
    int rem  = r & 32767;
    int gate = rem >> 13;
    int kc   = (rem >> 9) & 15;
    int ln   = (rem >> 3) & 63;
    int j    = rem & 7;
    int c = ln & 15, q = ln >> 4;
    int row  = (gate << 9) + (role << 4) + c;
    int colk = (kc << 5) + (q << 3) + j;
    float v;
    if (w == 6){
      v = decWih0[(size_t)row*23] * projW[colk];     // Wy = wcol0 (x) projW
    } else {
      const float* src = (w==0)?encWhh0:(w==1)?encWih1:(w==2)?encWhh1:
                         (w==3)?decWhh0:(w==4)?decWih1:decWhh1;
      v = src[(size_t)row*512 + colk];
    }
    uint16_t* dst = (w==0)?Whh0e:(w==1)?Wih1e:(w==2)?Whh1e:
                    (w==3)?Whh0d:(w==4)?Wih1d:(w==5)?Whh1d:Wyp;
    dst[r] = f2bf(v);
  } else if (i < 7*PREP_S + 524288){
    int r = i - 7*PREP_S; int b = r >> 11, j = r & 2047;
    float s = encbih0[j] + encbhh0[j];
    const float* e = emb + (size_t)turb[b]*16;
    const float* wr = encWih0 + (size_t)j*24 + 8;
    #pragma unroll
    for (int m = 0; m < 16; ++m) s += e[m]*wr[m];
    E0e[r] = s;
  } else if (i < 7*PREP_S + 1048576){
    int r = i - 7*PREP_S - 524288; int b = r >> 11, j = r & 2047;
    float s = decbih0[j] + decbhh0[j];
    const float* e = emb + (size_t)turb[b]*16;
    const float* wr = decWih0 + (size_t)j*23 + 7;
    #pragma unroll
    for (int m = 0; m < 16; ++m) s += e[m]*wr[m];
    E0d[r] = s;
  } else {
    int r = i - 7*PREP_S - 1048576;
    if (r < 2048)      b1e[r] = encbih1[r] + encbhh1[r];
    else if (r < 4096){ int j = r - 2048; b1d[j] = decbih1[j] + decbhh1[j]; }
    else              { int j = r - 4096; wcol0[j] = decWih0[(size_t)j*23]; }
  }
}

// ---------------------------------------------------------------------------
extern "C" void kernel_launch(void* const* d_in, const int* in_sizes, int n_in,
                              void* d_out, int out_size, void* d_ws, size_t ws_size,
                              hipStream_t stream)
{
  const float* xh      = (const float*)d_in[0];
  const float* xf      = (const float*)d_in[1];
  const float* y0v     = (const float*)d_in[2];
  const int*   turb    = (const int*)d_in[3];
  const float* emb     = (const float*)d_in[5];
  const float* encWih0 = (const float*)d_in[6];
  const float* encWhh0 = (const float*)d_in[7];
  const float* encbih0 = (const float*)d_in[8];
  const float* encbhh0 = (const float*)d_in[9];
  const float* encWih1 = (const float*)d_in[10];
  const float* encWhh1 = (const float*)d_in[11];
  const float* encbih1 = (const float*)d_in[12];
  const float* encbhh1 = (const float*)d_in[13];
  const float* decWih0 = (const float*)d_in[14];
  const float* decWhh0 = (const float*)d_in[15];
  const float* decbih0 = (const float*)d_in[16];
  const float* decbhh0 = (const float*)d_in[17];
  const float* decWih1 = (const float*)d_in[18];
  const float* decWhh1 = (const float*)d_in[19];
  const float* decbih1 = (const float*)d_in[20];
  const float* decbhh1 = (const float*)d_in[21];
  const float* projW   = (const float*)d_in[22];
  const float* projB   = (const float*)d_in[23];
  float* out = (float*)d_out;

  char* ws = (char*)d_ws;
  constexpr size_t SZW = (size_t)2048*512*2;        // 2 MiB per matrix
  constexpr size_t OFF_Whh0e = 0;
  constexpr size_t OFF_Wih1e = SZW;
  constexpr size_t OFF_Whh1e = 2*SZW;
  constexpr size_t OFF_Whh0d = 3*SZW;
  constexpr size_t OFF_Wih1d = 4*SZW;
  constexpr size_t OFF_Whh1d = 5*SZW;
  constexpr size_t OFF_Wy    = 6*SZW;
  constexpr size_t OFF_E0e   = 7*SZW;
  constexpr size_t OFF_E0d   = OFF_E0e + 2097152;
  constexpr size_t OFF_b1e   = OFF_E0d + 2097152;
  constexpr size_t OFF_b1d   = OFF_b1e + 8192;
  constexpr size_t OFF_wcol0 = OFF_b1d + 8192;
  constexpr size_t OFF_h0    = OFF_wcol0 + 8192;
  constexpr size_t OFF_h1    = OFF_h0 + 524288;
  constexpr size_t OFF_cnt   = OFF_h1 + 524288;
  constexpr size_t ZERO_BYTES = 2*524288 + 2048;    // h0,h1 ping-pong + counters+go+abort

  uint16_t* Whh0e = (uint16_t*)(ws + OFF_Whh0e);
  uint16_t* Wih1e = (uint16_t*)(ws + OFF_Wih1e);
  uint16_t* Whh1e = (uint16_t*)(ws + OFF_Whh1e);
  uint16_t* Whh0d = (uint16_t*)(ws + OFF_Whh0d);
  uint16_t* Wih1d = (uint16_t*)(ws + OFF_Wih1d);
  uint16_t* Whh1d = (uint16_t*)(ws + OFF_Whh1d);
  uint16_t* Wyp   = (uint16_t*)(ws + OFF_Wy);
  float* E0e   = (float*)(ws + OFF_E0e);
  float* E0d   = (float*)(ws + OFF_E0d);
  float* b1e   = (float*)(ws + OFF_b1e);
  float* b1d   = (float*)(ws + OFF_b1d);
  float* wcol0 = (float*)(ws + OFF_wcol0);
  uint16_t* h0p = (uint16_t*)(ws + OFF_h0);
  uint16_t* h1p = (uint16_t*)(ws + OFF_h1);
  unsigned* cntp = (unsigned*)(ws + OFF_cnt);

  hipMemsetAsync(ws + OFF_h0, 0, ZERO_BYTES, stream);

  prep_kernel<<<dim3((PREP_TOTAL + 255)/256), dim3(256), 0, stream>>>(
      encWih0, encWhh0, encWih1, encWhh1, decWih0, decWhh0, decWih1, decWhh1,
      encbih0, encbhh0, encbih1, encbhh1, decbih0, decbhh0, decbih1, decbhh1,
      projW, emb, turb,
      Whh0e, Wih1e, Whh1e, Whh0d, Wih1d, Whh1d, Wyp,
      E0e, E0d, b1e, b1d, wcol0);

  // Plain launch (proven R11/R14/R15). 128 blocks on 256 CUs @ 1 block/CU ->
  // co-residency with 2x slack; barrier spin is abort-guarded.
  seq2seq_main<<<dim3(NBLK), dim3(NTHR), 0, stream>>>(
      Whh0e, Wih1e, Whh1e, Whh0d, Wih1d, Whh1d, Wyp,
      E0e, E0d, b1e, b1d, wcol0,
      h0p, h1p, xh, xf, y0v,
      encWih0, decWih0, projW, projB,
      out, cntp);
}

// Round 14
// 8723.935 us; speedup vs baseline: 1.9136x; 1.1227x over previous
//
#include <hip/hip_runtime.h>
#include <stdint.h>

// ---------------------------------------------------------------------------
// R21 = R20 (9.79ms, best) + decoder L1 split-acc across the two phases.
//   R20's decoder: phase A = L0's {Whh0d,Wy} accK512 pair (L1 idle except
//   emitY); phase B = L1's {Whh1d,Wih1d} pair (L0 idle). But Whh1d*h1_{t-1}
//   needs only h1_{t-1} (available in phase A) -> move it to phase A and
//   carry the partial accumulator across the barrier in VGPRs. Phase B's
//   critical path drops to one accK512 + pointwise. Accumulation order
//   unchanged (Whh1d then Wih1d) -> bit-identical numerics.
//   Everything else byte-identical to R20:
//   - leader/go barrier; leader detect = 4 pipelined system-scope loads;
//     arrival = relaxed agent RMW; exit = acquire-inv (L2 refresh).
//   - h stores: 2-col packed system-scope atomic dword (write-through).
//   - h reads: plain b128, L2-shared.
//   - LDS-resident frag weights; E0/xw/b1/projW folds in registers.
//   - 2 supergroups x 64 roles, 128 blk x 512 thr, Wy rank-1 y-feedback,
//     emitY single-writer, abort-guarded spins, plain launch.
// ---------------------------------------------------------------------------

typedef __attribute__((ext_vector_type(8))) short bfx8;   // 8 bf16 (4 VGPRs)
typedef __attribute__((ext_vector_type(4))) float fx4;

#define NBLK 128
#define NTHR 512
#define BH   (256*512)

__device__ __forceinline__ unsigned short f2bf(float f){
  unsigned u = __float_as_uint(f);
  u += 0x7FFFu + ((u >> 16) & 1u);          // RNE
  return (unsigned short)(u >> 16);
}
__device__ __forceinline__ float bf2f(unsigned short b){
  return __uint_as_float(((unsigned)b) << 16);
}
__device__ __forceinline__ float sigm(float x){ return 1.0f/(1.0f + __expf(-x)); }
__device__ __forceinline__ float tanhf_(float x){
  x = fminf(12.0f, fmaxf(-12.0f, x));
  float e = __expf(2.0f*x);
  return (e - 1.0f)/(e + 1.0f);
}

// 64-block supergroup barrier, leader/go structure with load-based detect.
__device__ __forceinline__ bool groupbar(unsigned* cntg, int sub, unsigned gen,
                                         unsigned* go, bool leader,
                                         unsigned* abortf, volatile unsigned* s_abort){
  __syncthreads();
  if (threadIdx.x == 0){
    __hip_atomic_fetch_add(cntg + sub*32, 1u, __ATOMIC_RELAXED, __HIP_MEMORY_SCOPE_AGENT);
    const unsigned target = gen*16u;
    unsigned spins = 0;
    if (leader){
      for (;;){
        unsigned v0 = __hip_atomic_load(cntg +  0, __ATOMIC_RELAXED, __HIP_MEMORY_SCOPE_SYSTEM);
        unsigned v1 = __hip_atomic_load(cntg + 32, __ATOMIC_RELAXED, __HIP_MEMORY_SCOPE_SYSTEM);
        unsigned v2 = __hip_atomic_load(cntg + 64, __ATOMIC_RELAXED, __HIP_MEMORY_SCOPE_SYSTEM);
        unsigned v3 = __hip_atomic_load(cntg + 96, __ATOMIC_RELAXED, __HIP_MEMORY_SCOPE_SYSTEM);
        if (v0 >= target && v1 >= target && v2 >= target && v3 >= target) break;
        if (((++spins) & 1023u) == 0u){
          if (__hip_atomic_load(abortf, __ATOMIC_RELAXED, __HIP_MEMORY_SCOPE_AGENT) != 0u){
            *s_abort = 1u; break;
          }
          if (spins > (1u << 20)){
            __hip_atomic_store(abortf, 1u, __ATOMIC_RELAXED, __HIP_MEMORY_SCOPE_AGENT);
            *s_abort = 1u; break;
          }
        }
        __builtin_amdgcn_s_sleep(2);
      }
      __hip_atomic_store(go, gen, __ATOMIC_RELAXED, __HIP_MEMORY_SCOPE_SYSTEM);
    } else {
      while (__hip_atomic_load(go, __ATOMIC_RELAXED, __HIP_MEMORY_SCOPE_SYSTEM) < gen){
        if (((++spins) & 1023u) == 0u){
          if (__hip_atomic_load(abortf, __ATOMIC_RELAXED, __HIP_MEMORY_SCOPE_AGENT) != 0u){
            *s_abort = 1u; break;
          }
          if (spins > (1u << 20)){
            __hip_atomic_store(abortf, 1u, __ATOMIC_RELAXED, __HIP_MEMORY_SCOPE_AGENT);
            *s_abort = 1u; break;
          }
        }
        __builtin_amdgcn_s_sleep(2);
      }
    }
    (void)__hip_atomic_load(cntg, __ATOMIC_ACQUIRE, __HIP_MEMORY_SCOPE_AGENT);  // buffer_inv
  }
  __syncthreads();
  return *s_abort != 0u;
}

// K=512 accumulate: A rows from global h via PLAIN b128 loads (L2-cached,
// fresh after the barrier's inv); B = 4 gate-slices from LDS fragment layout.
__device__ __forceinline__ void accK512_lds(fx4* acc, const uint16_t* aq,
                                            const uint16_t* wl, int lane8){
  #pragma unroll
  for (int kc = 0; kc < 16; ++kc){
    bfx8 af = *(const bfx8*)(aq + kc*32);
    acc[0] = __builtin_amdgcn_mfma_f32_16x16x32_bf16(af, *(const bfx8*)(wl +         kc*512 + lane8), acc[0], 0, 0, 0);
    acc[1] = __builtin_amdgcn_mfma_f32_16x16x32_bf16(af, *(const bfx8*)(wl +  8192 + kc*512 + lane8), acc[1], 0, 0, 0);
    acc[2] = __builtin_amdgcn_mfma_f32_16x16x32_bf16(af, *(const bfx8*)(wl + 16384 + kc*512 + lane8), acc[2], 0, 0, 0);
    acc[3] = __builtin_amdgcn_mfma_f32_16x16x32_bf16(af, *(const bfx8*)(wl + 24576 + kc*512 + lane8), acc[3], 0, 0, 0);
  }
}

// LSTM pointwise; h store = packed 2-col SYSTEM-scope atomic dword.
__device__ __forceinline__ void pointwise(fx4* acc, fx4& creg, int bq, int u,
                                          int col, uint16_t* hout){
  #pragma unroll
  for (int r = 0; r < 4; ++r){
    float iv = sigm(acc[0][r]);
    float fv = sigm(acc[1][r]);
    float gv = tanhf_(acc[2][r]);
    float ov = sigm(acc[3][r]);
    float cn = fv * creg[r] + iv * gv;
    creg[r] = cn;
    unsigned hb = (unsigned)f2bf(ov * tanhf_(cn));
    unsigned nb = __shfl_xor(hb, 1);
    if ((col & 1) == 0){
      __hip_atomic_store((unsigned*)(hout + (size_t)(bq + r)*512 + u), hb | (nb << 16),
                         __ATOMIC_RELAXED, __HIP_MEMORY_SCOPE_SYSTEM);
    }
  }
}

__global__ void __launch_bounds__(NTHR, 2)
seq2seq_main(const uint16_t* __restrict__ Whh0e, const uint16_t* __restrict__ Wih1e,
             const uint16_t* __restrict__ Whh1e, const uint16_t* __restrict__ Whh0d,
             const uint16_t* __restrict__ Wih1d, const uint16_t* __restrict__ Whh1d,
             const uint16_t* __restrict__ Wy,
             const float* __restrict__ E0e, const float* __restrict__ E0d,
             const float* __restrict__ b1e, const float* __restrict__ b1d,
             const float* __restrict__ wcol0,
             uint16_t* h0buf, uint16_t* h1buf,
             const float* __restrict__ xh, const float* __restrict__ xf,
             const float* __restrict__ y0v,
             const float* __restrict__ encWih0, const float* __restrict__ decWih0,
             const float* __restrict__ projW, const float* __restrict__ projB,
             float* out, unsigned* cntBase)
{
  __shared__ uint4 smem4[8192];                 // 128 KiB static LDS
  __shared__ unsigned s_abort;
  uint16_t* smem = (uint16_t*)smem4;

  const int tid  = threadIdx.x;
  const int lane = tid & 63;
  const int wvi  = tid >> 6;                    // wave in block, 0..7
  const int gh   = wvi >> 2;                    // batch-half within supergroup
  const int wv4  = wvi & 3;                     // M-tile index within half
  const int sg   = blockIdx.x >> 6;             // supergroup (128 batch rows)
  const int k    = blockIdx.x & 63;             // role: 0..31 L0, 32..63 L1
  const bool isL0 = (k < 32);
  const int role = isL0 ? k : k - 32;           // u-slice index, 0..31
  const int col  = lane & 15;
  const int quad = lane >> 4;
  const int g    = (sg << 1) + gh;              // logical 64-row group, 0..3
  const int rowbase = (g << 6) + (wv4 << 4);    // wave's 16-row M-tile base
  const int bq   = rowbase + (quad << 2);
  const int u    = (role << 4) + col;
  const int lane8 = lane << 3;
  unsigned* cntg = cntBase + (size_t)sg * 128;  // 4 counters x 128B / supergroup
  unsigned* abortf = cntBase + 256;             // abort flag (own line, zeroed)
  unsigned* go     = cntBase + 288 + sg*32;     // go word (own line, zeroed)
  const bool leader = (k == 0);
  const int sub  = k >> 4;
  unsigned gen = 0;
  fx4 creg = {0.f, 0.f, 0.f, 0.f};              // c0 (L0) or c1 (L1)
  const float projB_val = projB[0];
  const int hoff = (rowbase + col)*512 + (quad << 3);

  if (tid == 0) s_abort = 0u;

  uint16_t *h0A = h0buf, *h0B = h0buf + BH;
  uint16_t *h1A = h1buf, *h1B = h1buf + BH;

  // ---- stage encoder weight slices into LDS ----
  if (isL0){
    const uint4* s0 = (const uint4*)(Whh0e + (size_t)role*32768);
    for (int i = tid; i < 4096; i += NTHR) smem4[i] = s0[i];
  } else {
    const uint4* s0 = (const uint4*)(Wih1e + (size_t)role*32768);
    const uint4* s1 = (const uint4*)(Whh1e + (size_t)role*32768);
    for (int i = tid; i < 4096; i += NTHR){ smem4[i] = s0[i]; smem4[4096+i] = s1[i]; }
  }

  // ---- hoist per-lane constants into registers ----
  float e0r[4][4], xw[4][8], wc[4], b1r[4], pw8[8];
  if (isL0){
    #pragma unroll
    for (int gg = 0; gg < 4; ++gg){
      #pragma unroll
      for (int r = 0; r < 4; ++r)
        e0r[gg][r] = E0e[(size_t)(bq + r)*2048 + (gg << 9) + u];
      #pragma unroll
      for (int kk = 0; kk < 8; ++kk)
        xw[gg][kk] = encWih0[(size_t)((gg << 9) + u)*24 + kk];
    }
  } else {
    #pragma unroll
    for (int gg = 0; gg < 4; ++gg) b1r[gg] = b1e[(gg << 9) + u];
    if (k < 36){                                // emitY blocks k=32..35
      #pragma unroll
      for (int kk = 0; kk < 8; ++kk) pw8[kk] = projW[lane8 + kk];
    }
  }
  __syncthreads();

  auto encCompute = [&](int tt, const uint16_t* h0c, uint16_t* h0n){
    fx4 acc[4];
    #pragma unroll
    for (int gg = 0; gg < 4; ++gg)
      #pragma unroll
      for (int r = 0; r < 4; ++r) acc[gg][r] = e0r[gg][r];
    float xv[4][8];
    #pragma unroll
    for (int r = 0; r < 4; ++r){
      const float* xr = xh + ((size_t)(bq + r)*288 + tt)*8;
      #pragma unroll
      for (int kk = 0; kk < 8; ++kk) xv[r][kk] = xr[kk];
    }
    accK512_lds(acc, h0c + hoff, smem, lane8);
    #pragma unroll
    for (int gg = 0; gg < 4; ++gg)
      #pragma unroll
      for (int kk = 0; kk < 8; ++kk){
        float w = xw[gg][kk];
        #pragma unroll
        for (int r = 0; r < 4; ++r) acc[gg][r] += w * xv[r][kk];
      }
    pointwise(acc, creg, bq, u, col, h0n);
  };

  // emitY: blocks k=32..35; per half, wave wv4 covers 4 rows. Plain loads
  // (fresh after barrier inv); single-writer out stores.
  auto emitY = [&](const uint16_t* h1cur, int tt){
    int rb = (g << 6) + ((k - 32) << 4) + (wv4 << 2);
    #pragma unroll 1
    for (int j = 0; j < 4; ++j){
      int b = rb + j;
      const uint16_t* hr = h1cur + (size_t)b*512 + lane8;
      float part = 0.f;
      #pragma unroll
      for (int kk = 0; kk < 8; ++kk) part += bf2f(hr[kk]) * pw8[kk];
      #pragma unroll
      for (int off = 32; off > 0; off >>= 1) part += __shfl_down(part, off);
      if (lane == 0) out[(size_t)b*288 + tt] = part + projB_val;
    }
  };

  // ---- prologue: enc L0 t=0 (h_{-1}=0 via memset) ----
  if (isL0) encCompute(0, h0A, h0B);
  if (groupbar(cntg, sub, ++gen, go, leader, abortf, &s_abort)) return;
  { uint16_t* t_ = h0A; h0A = h0B; h0B = t_; }   // h0A = h0_0

  // ---- encoder: 1 barrier/step; L1_t || L0_{t+1} ----
  #pragma unroll 1
  for (int t = 0; t < 288; ++t){
    if (isL0){
      if (t < 287) encCompute(t + 1, h0A, h0B);
    } else {
      fx4 acc[4];
      #pragma unroll
      for (int gg = 0; gg < 4; ++gg)
        #pragma unroll
        for (int r = 0; r < 4; ++r) acc[gg][r] = b1r[gg];
      accK512_lds(acc, h0A + hoff, smem, lane8);            // Wih1e * h0_t
      accK512_lds(acc, h1A + hoff, smem + 32768, lane8);    // Whh1e * h1_{t-1}
      pointwise(acc, creg, bq, u, col, h1B);
    }
    if (groupbar(cntg, sub, ++gen, go, leader, abortf, &s_abort)) return;
    { uint16_t* t_ = h1A; h1A = h1B; h1B = t_; }
    if (t < 287){ uint16_t* t_ = h0A; h0A = h0B; h0B = t_; }
  }
  // h0A = h0_287, h1A = h1_287; c continues into decoder.

  // ---- restage decoder weights + regs (block-local) ----
  if (isL0){
    const uint4* s0 = (const uint4*)(Whh0d + (size_t)role*32768);
    const uint4* s1 = (const uint4*)(Wy    + (size_t)role*32768);
    for (int i = tid; i < 4096; i += NTHR){ smem4[i] = s0[i]; smem4[4096+i] = s1[i]; }
    #pragma unroll
    for (int gg = 0; gg < 4; ++gg){
      #pragma unroll
      for (int r = 0; r < 4; ++r)
        e0r[gg][r] = E0d[(size_t)(bq + r)*2048 + (gg << 9) + u];
      #pragma unroll
      for (int kk = 0; kk < 6; ++kk)
        xw[gg][kk] = decWih0[(size_t)((gg << 9) + u)*23 + 1 + kk];
      wc[gg] = wcol0[(gg << 9) + u];
    }
  } else {
    const uint4* s0 = (const uint4*)(Wih1d + (size_t)role*32768);
    const uint4* s1 = (const uint4*)(Whh1d + (size_t)role*32768);
    for (int i = tid; i < 4096; i += NTHR){ smem4[i] = s0[i]; smem4[4096+i] = s1[i]; }
    #pragma unroll
    for (int gg = 0; gg < 4; ++gg) b1r[gg] = b1d[(gg << 9) + u];
  }
  __syncthreads();

  auto decCompute = [&](int tt, const uint16_t* h0c, const uint16_t* h1c,
                        uint16_t* h0n){
    fx4 acc[4];
    #pragma unroll
    for (int gg = 0; gg < 4; ++gg)
      #pragma unroll
      for (int r = 0; r < 4; ++r) acc[gg][r] = e0r[gg][r];
    accK512_lds(acc, h0c + hoff, smem, lane8);              // Whh0d
    if (tt > 0)
      accK512_lds(acc, h1c + hoff, smem + 32768, lane8);    // Wy
    float s[4];
    #pragma unroll
    for (int r = 0; r < 4; ++r) s[r] = (tt == 0) ? y0v[bq + r] : projB_val;
    float xv[4][6];
    #pragma unroll
    for (int r = 0; r < 4; ++r){
      const float* xr = xf + ((size_t)(bq + r)*288 + tt)*6;
      #pragma unroll
      for (int kk = 0; kk < 6; ++kk) xv[r][kk] = xr[kk];
    }
    #pragma unroll
    for (int gg = 0; gg < 4; ++gg){
      #pragma unroll
      for (int r = 0; r < 4; ++r) acc[gg][r] += wc[gg] * s[r];
      #pragma unroll
      for (int kk = 0; kk < 6; ++kk){
        float w = xw[gg][kk];
        #pragma unroll
        for (int r = 0; r < 4; ++r) acc[gg][r] += w * xv[r][kk];
      }
    }
    pointwise(acc, creg, bq, u, col, h0n);
  };

  // ---- decoder: 2 barriers/step; L1's accK512 pair SPLIT across phases ----
  // Phase A: L0 computes h0_t (Whh0d+Wy); L1 starts accL1 = b1 + Whh1d*h1_{t-1}
  //          (carried in VGPRs across the barrier) + emitY(t-1) for k<36.
  // Phase B: L1 finishes accL1 += Wih1d*h0_t, pointwise -> h1_t.
  // Accumulation order (Whh1d then Wih1d) identical to R20 -> same numerics.
  #pragma unroll 1
  for (int t = 0; t < 288; ++t){
    fx4 accL1[4];
    if (isL0){
      decCompute(t, h0A, h1A, h0B);
    } else {
      #pragma unroll
      for (int gg = 0; gg < 4; ++gg)
        #pragma unroll
        for (int r = 0; r < 4; ++r) accL1[gg][r] = b1r[gg];
      accK512_lds(accL1, h1A + hoff, smem + 32768, lane8);  // Whh1d * h1_{t-1}
      if (k < 36 && t > 0) emitY(h1A, t - 1);
    }
    if (groupbar(cntg, sub, ++gen, go, leader, abortf, &s_abort)) return;
    if (!isL0){
      accK512_lds(accL1, h0B + hoff, smem, lane8);          // Wih1d * h0_t
      pointwise(accL1, creg, bq, u, col, h1B);
    }
    if (groupbar(cntg, sub, ++gen, go, leader, abortf, &s_abort)) return;
    { uint16_t* t_ = h0A; h0A = h0B; h0B = t_; }
    { uint16_t* t_ = h1A; h1A = h1B; h1B = t_; }
  }

  // final y_287 (h1A = h1_287, published by last barrier)
  if (!isL0 && k < 36) emitY(h1A, 287);
}

// ---------------- prep: frag-ordered bf16 weights (+Wy), emb+bias folds ----
#define PREP_S 1048576
#define PREP_TOTAL (7*PREP_S + 1048576 + 6144)

__global__ void __launch_bounds__(256)
prep_kernel(const float* __restrict__ encWih0, const float* __restrict__ encWhh0,
            const float* __restrict__ encWih1, const float* __restrict__ encWhh1,
            const float* __restrict__ decWih0, const float* __restrict__ decWhh0,
            const float* __restrict__ decWih1, const float* __restrict__ decWhh1,
            const float* __restrict__ encbih0, const float* __restrict__ encbhh0,
            const float* __restrict__ encbih1, const float* __restrict__ encbhh1,
            const float* __restrict__ decbih0, const float* __restrict__ decbhh0,
            const float* __restrict__ decbih1, const float* __restrict__ decbhh1,
            const float* __restrict__ projW, const float* __restrict__ emb,
            const int* __restrict__ turb,
            uint16_t* Whh0e, uint16_t* Wih1e, uint16_t* Whh1e,
            uint16_t* Whh0d, uint16_t* Wih1d, uint16_t* Whh1d, uint16_t* Wyp,
            float* E0e, float* E0d, float* b1e, float* b1d, float* wcol0)
{
  int i = blockIdx.x*256 + threadIdx.x;
  if (i >= PREP_TOTAL) return;
  if (i < 7*PREP_S){
    // fragment reorder: dest = role*32768 + gate*8192 + kc*512 + lane*8 + j
    // value = W[gate*512 + role*16 + (lane&15)][kc*32 + (lane>>4)*8 + j]
    int w = i >> 20, r = i & (PREP_S - 1);
    int role = r >> 15;
    int rem  = r & 32767;
    int gate = rem >> 13;
    int kc   = (rem >> 9) & 15;
    int ln   = (rem >> 3) & 63;
    int j    = rem & 7;
    int c = ln & 15, q = ln >> 4;
    int row  = (gate << 9) + (role << 4) + c;
    int colk = (kc << 5) + (q << 3) + j;
    float v;
    if (w == 6){
      v = decWih0[(size_t)row*23] * projW[colk];     // Wy = wcol0 (x) projW
    } else {
      const float* src = (w==0)?encWhh0:(w==1)?encWih1:(w==2)?encWhh1:
                         (w==3)?decWhh0:(w==4)?decWih1:decWhh1;
      v = src[(size_t)row*512 + colk];
    }
    uint16_t* dst = (w==0)?Whh0e:(w==1)?Wih1e:(w==2)?Whh1e:
                    (w==3)?Whh0d:(w==4)?Wih1d:(w==5)?Whh1d:Wyp;
    dst[r] = f2bf(v);
  } else if (i < 7*PREP_S + 524288){
    int r = i - 7*PREP_S; int b = r >> 11, j = r & 2047;
    float s = encbih0[j] + encbhh0[j];
    const float* e = emb + (size_t)turb[b]*16;
    const float* wr = encWih0 + (size_t)j*24 + 8;
    #pragma unroll
    for (int m = 0; m < 16; ++m) s += e[m]*wr[m];
    E0e[r] = s;
  } else if (i < 7*PREP_S + 1048576){
    int r = i - 7*PREP_S - 524288; int b = r >> 11, j = r & 2047;
    float s = decbih0[j] + decbhh0[j];
    const float* e = emb + (size_t)turb[b]*16;
    const float* wr = decWih0 + (size_t)j*23 + 7;
    #pragma unroll
    for (int m = 0; m < 16; ++m) s += e[m]*wr[m];
    E0d[r] = s;
  } else {
    int r = i - 7*PREP_S - 1048576;
    if (r < 2048)      b1e[r] = encbih1[r] + encbhh1[r];
    else if (r < 4096){ int j = r - 2048; b1d[j] = decbih1[j] + decbhh1[j]; }
    else              { int j = r - 4096; wcol0[j] = decWih0[(size_t)j*23]; }
  }
}

// ---------------------------------------------------------------------------
extern "C" void kernel_launch(void* const* d_in, const int* in_sizes, int n_in,
                              void* d_out, int out_size, void* d_ws, size_t ws_size,
                              hipStream_t stream)
{
  const float* xh      = (const float*)d_in[0];
  const float* xf      = (const float*)d_in[1];
  const float* y0v     = (const float*)d_in[2];
  const int*   turb    = (const int*)d_in[3];
  const float* emb     = (const float*)d_in[5];
  const float* encWih0 = (const float*)d_in[6];
  const float* encWhh0 = (const float*)d_in[7];
  const float* encbih0 = (const float*)d_in[8];
  const float* encbhh0 = (const float*)d_in[9];
  const float* encWih1 = (const float*)d_in[10];
  const float* encWhh1 = (const float*)d_in[11];
  const float* encbih1 = (const float*)d_in[12];
  const float* encbhh1 = (const float*)d_in[13];
  const float* decWih0 = (const float*)d_in[14];
  const float* decWhh0 = (const float*)d_in[15];
  const float* decbih0 = (const float*)d_in[16];
  const float* decbhh0 = (const float*)d_in[17];
  const float* decWih1 = (const float*)d_in[18];
  const float* decWhh1 = (const float*)d_in[19];
  const float* decbih1 = (const float*)d_in[20];
  const float* decbhh1 = (const float*)d_in[21];
  const float* projW   = (const float*)d_in[22];
  const float* projB   = (const float*)d_in[23];
  float* out = (float*)d_out;

  char* ws = (char*)d_ws;
  constexpr size_t SZW = (size_t)2048*512*2;        // 2 MiB per matrix
  constexpr size_t OFF_Whh0e = 0;
  constexpr size_t OFF_Wih1e = SZW;
  constexpr size_t OFF_Whh1e = 2*SZW;
  constexpr size_t OFF_Whh0d = 3*SZW;
  constexpr size_t OFF_Wih1d = 4*SZW;
  constexpr size_t OFF_Whh1d = 5*SZW;
  constexpr size_t OFF_Wy    = 6*SZW;
  constexpr size_t OFF_E0e   = 7*SZW;
  constexpr size_t OFF_E0d   = OFF_E0e + 2097152;
  constexpr size_t OFF_b1e   = OFF_E0d + 2097152;
  constexpr size_t OFF_b1d   = OFF_b1e + 8192;
  constexpr size_t OFF_wcol0 = OFF_b1d + 8192;
  constexpr size_t OFF_h0    = OFF_wcol0 + 8192;
  constexpr size_t OFF_h1    = OFF_h0 + 524288;
  constexpr size_t OFF_cnt   = OFF_h1 + 524288;
  constexpr size_t ZERO_BYTES = 2*524288 + 2048;    // h0,h1 ping-pong + counters+go+abort

  uint16_t* Whh0e = (uint16_t*)(ws + OFF_Whh0e);
  uint16_t* Wih1e = (uint16_t*)(ws + OFF_Wih1e);
  uint16_t* Whh1e = (uint16_t*)(ws + OFF_Whh1e);
  uint16_t* Whh0d = (uint16_t*)(ws + OFF_Whh0d);
  uint16_t* Wih1d = (uint16_t*)(ws + OFF_Wih1d);
  uint16_t* Whh1d = (uint16_t*)(ws + OFF_Whh1d);
  uint16_t* Wyp   = (uint16_t*)(ws + OFF_Wy);
  float* E0e   = (float*)(ws + OFF_E0e);
  float* E0d   = (float*)(ws + OFF_E0d);
  float* b1e   = (float*)(ws + OFF_b1e);
  float* b1d   = (float*)(ws + OFF_b1d);
  float* wcol0 = (float*)(ws + OFF_wcol0);
  uint16_t* h0p = (uint16_t*)(ws + OFF_h0);
  uint16_t* h1p = (uint16_t*)(ws + OFF_h1);
  unsigned* cntp = (unsigned*)(ws + OFF_cnt);

  hipMemsetAsync(ws + OFF_h0, 0, ZERO_BYTES, stream);

  prep_kernel<<<dim3((PREP_TOTAL + 255)/256), dim3(256), 0, stream>>>(
      encWih0, encWhh0, encWih1, encWhh1, decWih0, decWhh0, decWih1, decWhh1,
      encbih0, encbhh0, encbih1, encbhh1, decbih0, decbhh0, decbih1, decbhh1,
      projW, emb, turb,
      Whh0e, Wih1e, Whh1e, Whh0d, Wih1d, Whh1d, Wyp,
      E0e, E0d, b1e, b1d, wcol0);

  // Plain launch (proven R11/R14/R15/R20). 128 blocks on 256 CUs @ 1 block/CU
  // -> co-residency with 2x slack; barrier spin is abort-guarded.
  seq2seq_main<<<dim3(NBLK), dim3(NTHR), 0, stream>>>(
      Whh0e, Wih1e, Whh1e, Whh0d, Wih1d, Whh1d, Wyp,
      E0e, E0d, b1e, b1d, wcol0,
      h0p, h1p, xh, xf, y0v,
      encWih0, decWih0, projW, projB,
      out, cntp);
}

// Round 16
// 7752.523 us; speedup vs baseline: 2.1533x; 1.1253x over previous
//
#include <hip/hip_runtime.h>
#include <stdint.h>

// ---------------------------------------------------------------------------
// R23 = R22 resubmitted verbatim (R22 hit "container failed twice" = infra
// flake; abort-guarded spins make a true deadlock impossible to wedge, and a
// lane-level hazard audit of the L0 split-acc found no defect).
// R22 = R21 (8.72ms, best) + decoder L0 split-acc (mirror of R21's L1 split):
//   Phase A: L0 {Wy*h1_{t-1} + wc*s + x + pointwise}, L1 {Whh1d + emitY}
//   Phase B: L1 {Wih1d + pointwise},  L0 {prefetch E0d + Whh0d*h0_t}
//   -> every decoder phase has exactly ONE accK512 per role. Accumulation
//   order e0r -> Whh0d -> Wy -> wc*s -> x unchanged -> bit-identical.
//   t=0: accL0 seeded after restage from h0_287; Wy skipped (y0 path).
//   Everything else byte-identical to R21 (leader/go barrier with load-based
//   detect + acquire-inv exit, system-scope packed h stores, plain b128
//   L2-shared h reads, LDS-resident frag weights, emitY, abort guard).
// ---------------------------------------------------------------------------

typedef __attribute__((ext_vector_type(8))) short bfx8;   // 8 bf16 (4 VGPRs)
typedef __attribute__((ext_vector_type(4))) float fx4;

#define NBLK 128
#define NTHR 512
#define BH   (256*512)

__device__ __forceinline__ unsigned short f2bf(float f){
  unsigned u = __float_as_uint(f);
  u += 0x7FFFu + ((u >> 16) & 1u);          // RNE
  return (unsigned short)(u >> 16);
}
__device__ __forceinline__ float bf2f(unsigned short b){
  return __uint_as_float(((unsigned)b) << 16);
}
__device__ __forceinline__ float sigm(float x){ return 1.0f/(1.0f + __expf(-x)); }
__device__ __forceinline__ float tanhf_(float x){
  x = fminf(12.0f, fmaxf(-12.0f, x));
  float e = __expf(2.0f*x);
  return (e - 1.0f)/(e + 1.0f);
}

// 64-block supergroup barrier, leader/go structure with load-based detect.
__device__ __forceinline__ bool groupbar(unsigned* cntg, int sub, unsigned gen,
                                         unsigned* go, bool leader,
                                         unsigned* abortf, volatile unsigned* s_abort){
  __syncthreads();
  if (threadIdx.x == 0){
    __hip_atomic_fetch_add(cntg + sub*32, 1u, __ATOMIC_RELAXED, __HIP_MEMORY_SCOPE_AGENT);
    const unsigned target = gen*16u;
    unsigned spins = 0;
    if (leader){
      for (;;){
        unsigned v0 = __hip_atomic_load(cntg +  0, __ATOMIC_RELAXED, __HIP_MEMORY_SCOPE_SYSTEM);
        unsigned v1 = __hip_atomic_load(cntg + 32, __ATOMIC_RELAXED, __HIP_MEMORY_SCOPE_SYSTEM);
        unsigned v2 = __hip_atomic_load(cntg + 64, __ATOMIC_RELAXED, __HIP_MEMORY_SCOPE_SYSTEM);
        unsigned v3 = __hip_atomic_load(cntg + 96, __ATOMIC_RELAXED, __HIP_MEMORY_SCOPE_SYSTEM);
        if (v0 >= target && v1 >= target && v2 >= target && v3 >= target) break;
        if (((++spins) & 1023u) == 0u){
          if (__hip_atomic_load(abortf, __ATOMIC_RELAXED, __HIP_MEMORY_SCOPE_AGENT) != 0u){
            *s_abort = 1u; break;
          }
          if (spins > (1u << 20)){
            __hip_atomic_store(abortf, 1u, __ATOMIC_RELAXED, __HIP_MEMORY_SCOPE_AGENT);
            *s_abort = 1u; break;
          }
        }
        __builtin_amdgcn_s_sleep(2);
      }
      __hip_atomic_store(go, gen, __ATOMIC_RELAXED, __HIP_MEMORY_SCOPE_SYSTEM);
    } else {
      while (__hip_atomic_load(go, __ATOMIC_RELAXED, __HIP_MEMORY_SCOPE_SYSTEM) < gen){
        if (((++spins) & 1023u) == 0u){
          if (__hip_atomic_load(abortf, __ATOMIC_RELAXED, __HIP_MEMORY_SCOPE_AGENT) != 0u){
            *s_abort = 1u; break;
          }
          if (spins > (1u << 20)){
            __hip_atomic_store(abortf, 1u, __ATOMIC_RELAXED, __HIP_MEMORY_SCOPE_AGENT);
            *s_abort = 1u; break;
          }
        }
        __builtin_amdgcn_s_sleep(2);
      }
    }
    (void)__hip_atomic_load(cntg, __ATOMIC_ACQUIRE, __HIP_MEMORY_SCOPE_AGENT);  // buffer_inv
  }
  __syncthreads();
  return *s_abort != 0u;
}

// K=512 accumulate: A rows from global h via PLAIN b128 loads (L2-cached,
// fresh after the barrier's inv); B = 4 gate-slices from LDS fragment layout.
__device__ __forceinline__ void accK512_lds(fx4* acc, const uint16_t* aq,
                                            const uint16_t* wl, int lane8){
  #pragma unroll
  for (int kc = 0; kc < 16; ++kc){
    bfx8 af = *(const bfx8*)(aq + kc*32);
    acc[0] = __builtin_amdgcn_mfma_f32_16x16x32_bf16(af, *(const bfx8*)(wl +         kc*512 + lane8), acc[0], 0, 0, 0);
    acc[1] = __builtin_amdgcn_mfma_f32_16x16x32_bf16(af, *(const bfx8*)(wl +  8192 + kc*512 + lane8), acc[1], 0, 0, 0);
    acc[2] = __builtin_amdgcn_mfma_f32_16x16x32_bf16(af, *(const bfx8*)(wl + 16384 + kc*512 + lane8), acc[2], 0, 0, 0);
    acc[3] = __builtin_amdgcn_mfma_f32_16x16x32_bf16(af, *(const bfx8*)(wl + 24576 + kc*512 + lane8), acc[3], 0, 0, 0);
  }
}

// LSTM pointwise; h store = packed 2-col SYSTEM-scope atomic dword.
__device__ __forceinline__ void pointwise(fx4* acc, fx4& creg, int bq, int u,
                                          int col, uint16_t* hout){
  #pragma unroll
  for (int r = 0; r < 4; ++r){
    float iv = sigm(acc[0][r]);
    float fv = sigm(acc[1][r]);
    float gv = tanhf_(acc[2][r]);
    float ov = sigm(acc[3][r]);
    float cn = fv * creg[r] + iv * gv;
    creg[r] = cn;
    unsigned hb = (unsigned)f2bf(ov * tanhf_(cn));
    unsigned nb = __shfl_xor(hb, 1);
    if ((col & 1) == 0){
      __hip_atomic_store((unsigned*)(hout + (size_t)(bq + r)*512 + u), hb | (nb << 16),
                         __ATOMIC_RELAXED, __HIP_MEMORY_SCOPE_SYSTEM);
    }
  }
}

__global__ void __launch_bounds__(NTHR, 2)
seq2seq_main(const uint16_t* __restrict__ Whh0e, const uint16_t* __restrict__ Wih1e,
             const uint16_t* __restrict__ Whh1e, const uint16_t* __restrict__ Whh0d,
             const uint16_t* __restrict__ Wih1d, const uint16_t* __restrict__ Whh1d,
             const uint16_t* __restrict__ Wy,
             const float* __restrict__ E0e, const float* __restrict__ E0d,
             const float* __restrict__ b1e, const float* __restrict__ b1d,
             const float* __restrict__ wcol0,
             uint16_t* h0buf, uint16_t* h1buf,
             const float* __restrict__ xh, const float* __restrict__ xf,
             const float* __restrict__ y0v,
             const float* __restrict__ encWih0, const float* __restrict__ decWih0,
             const float* __restrict__ projW, const float* __restrict__ projB,
             float* out, unsigned* cntBase)
{
  __shared__ uint4 smem4[8192];                 // 128 KiB static LDS
  __shared__ unsigned s_abort;
  uint16_t* smem = (uint16_t*)smem4;

  const int tid  = threadIdx.x;
  const int lane = tid & 63;
  const int wvi  = tid >> 6;                    // wave in block, 0..7
  const int gh   = wvi >> 2;                    // batch-half within supergroup
  const int wv4  = wvi & 3;                     // M-tile index within half
  const int sg   = blockIdx.x >> 6;             // supergroup (128 batch rows)
  const int k    = blockIdx.x & 63;             // role: 0..31 L0, 32..63 L1
  const bool isL0 = (k < 32);
  const int role = isL0 ? k : k - 32;           // u-slice index, 0..31
  const int col  = lane & 15;
  const int quad = lane >> 4;
  const int g    = (sg << 1) + gh;              // logical 64-row group, 0..3
  const int rowbase = (g << 6) + (wv4 << 4);    // wave's 16-row M-tile base
  const int bq   = rowbase + (quad << 2);
  const int u    = (role << 4) + col;
  const int lane8 = lane << 3;
  unsigned* cntg = cntBase + (size_t)sg * 128;  // 4 counters x 128B / supergroup
  unsigned* abortf = cntBase + 256;             // abort flag (own line, zeroed)
  unsigned* go     = cntBase + 288 + sg*32;     // go word (own line, zeroed)
  const bool leader = (k == 0);
  const int sub  = k >> 4;
  unsigned gen = 0;
  fx4 creg = {0.f, 0.f, 0.f, 0.f};              // c0 (L0) or c1 (L1)
  const float projB_val = projB[0];
  const int hoff = (rowbase + col)*512 + (quad << 3);

  if (tid == 0) s_abort = 0u;

  uint16_t *h0A = h0buf, *h0B = h0buf + BH;
  uint16_t *h1A = h1buf, *h1B = h1buf + BH;

  // ---- stage encoder weight slices into LDS ----
  if (isL0){
    const uint4* s0 = (const uint4*)(Whh0e + (size_t)role*32768);
    for (int i = tid; i < 4096; i += NTHR) smem4[i] = s0[i];
  } else {
    const uint4* s0 = (const uint4*)(Wih1e + (size_t)role*32768);
    const uint4* s1 = (const uint4*)(Whh1e + (size_t)role*32768);
    for (int i = tid; i < 4096; i += NTHR){ smem4[i] = s0[i]; smem4[4096+i] = s1[i]; }
  }

  // ---- hoist per-lane constants into registers ----
  float e0r[4][4], xw[4][8], wc[4], b1r[4], pw8[8];
  if (isL0){
    #pragma unroll
    for (int gg = 0; gg < 4; ++gg){
      #pragma unroll
      for (int r = 0; r < 4; ++r)
        e0r[gg][r] = E0e[(size_t)(bq + r)*2048 + (gg << 9) + u];
      #pragma unroll
      for (int kk = 0; kk < 8; ++kk)
        xw[gg][kk] = encWih0[(size_t)((gg << 9) + u)*24 + kk];
    }
  } else {
    #pragma unroll
    for (int gg = 0; gg < 4; ++gg) b1r[gg] = b1e[(gg << 9) + u];
    if (k < 36){                                // emitY blocks k=32..35
      #pragma unroll
      for (int kk = 0; kk < 8; ++kk) pw8[kk] = projW[lane8 + kk];
    }
  }
  __syncthreads();

  auto encCompute = [&](int tt, const uint16_t* h0c, uint16_t* h0n){
    fx4 acc[4];
    #pragma unroll
    for (int gg = 0; gg < 4; ++gg)
      #pragma unroll
      for (int r = 0; r < 4; ++r) acc[gg][r] = e0r[gg][r];
    float xv[4][8];
    #pragma unroll
    for (int r = 0; r < 4; ++r){
      const float* xr = xh + ((size_t)(bq + r)*288 + tt)*8;
      #pragma unroll
      for (int kk = 0; kk < 8; ++kk) xv[r][kk] = xr[kk];
    }
    accK512_lds(acc, h0c + hoff, smem, lane8);
    #pragma unroll
    for (int gg = 0; gg < 4; ++gg)
      #pragma unroll
      for (int kk = 0; kk < 8; ++kk){
        float w = xw[gg][kk];
        #pragma unroll
        for (int r = 0; r < 4; ++r) acc[gg][r] += w * xv[r][kk];
      }
    pointwise(acc, creg, bq, u, col, h0n);
  };

  // emitY: blocks k=32..35; per half, wave wv4 covers 4 rows. Plain loads
  // (fresh after barrier inv); single-writer out stores.
  auto emitY = [&](const uint16_t* h1cur, int tt){
    int rb = (g << 6) + ((k - 32) << 4) + (wv4 << 2);
    #pragma unroll 1
    for (int j = 0; j < 4; ++j){
      int b = rb + j;
      const uint16_t* hr = h1cur + (size_t)b*512 + lane8;
      float part = 0.f;
      #pragma unroll
      for (int kk = 0; kk < 8; ++kk) part += bf2f(hr[kk]) * pw8[kk];
      #pragma unroll
      for (int off = 32; off > 0; off >>= 1) part += __shfl_down(part, off);
      if (lane == 0) out[(size_t)b*288 + tt] = part + projB_val;
    }
  };

  // ---- prologue: enc L0 t=0 (h_{-1}=0 via memset) ----
  if (isL0) encCompute(0, h0A, h0B);
  if (groupbar(cntg, sub, ++gen, go, leader, abortf, &s_abort)) return;
  { uint16_t* t_ = h0A; h0A = h0B; h0B = t_; }   // h0A = h0_0

  // ---- encoder: 1 barrier/step; L1_t || L0_{t+1} ----
  #pragma unroll 1
  for (int t = 0; t < 288; ++t){
    if (isL0){
      if (t < 287) encCompute(t + 1, h0A, h0B);
    } else {
      fx4 acc[4];
      #pragma unroll
      for (int gg = 0; gg < 4; ++gg)
        #pragma unroll
        for (int r = 0; r < 4; ++r) acc[gg][r] = b1r[gg];
      accK512_lds(acc, h0A + hoff, smem, lane8);            // Wih1e * h0_t
      accK512_lds(acc, h1A + hoff, smem + 32768, lane8);    // Whh1e * h1_{t-1}
      pointwise(acc, creg, bq, u, col, h1B);
    }
    if (groupbar(cntg, sub, ++gen, go, leader, abortf, &s_abort)) return;
    { uint16_t* t_ = h1A; h1A = h1B; h1B = t_; }
    if (t < 287){ uint16_t* t_ = h0A; h0A = h0B; h0B = t_; }
  }
  // h0A = h0_287, h1A = h1_287; c continues into decoder.

  // ---- restage decoder weights + regs (block-local) ----
  if (isL0){
    const uint4* s0 = (const uint4*)(Whh0d + (size_t)role*32768);
    const uint4* s1 = (const uint4*)(Wy    + (size_t)role*32768);
    for (int i = tid; i < 4096; i += NTHR){ smem4[i] = s0[i]; smem4[4096+i] = s1[i]; }
    #pragma unroll
    for (int gg = 0; gg < 4; ++gg){
      #pragma unroll
      for (int r = 0; r < 4; ++r)
        e0r[gg][r] = E0d[(size_t)(bq + r)*2048 + (gg << 9) + u];
      #pragma unroll
      for (int kk = 0; kk < 6; ++kk)
        xw[gg][kk] = decWih0[(size_t)((gg << 9) + u)*23 + 1 + kk];
      wc[gg] = wcol0[(gg << 9) + u];
    }
  } else {
    const uint4* s0 = (const uint4*)(Wih1d + (size_t)role*32768);
    const uint4* s1 = (const uint4*)(Whh1d + (size_t)role*32768);
    for (int i = tid; i < 4096; i += NTHR){ smem4[i] = s0[i]; smem4[4096+i] = s1[i]; }
    #pragma unroll
    for (int gg = 0; gg < 4; ++gg) b1r[gg] = b1d[(gg << 9) + u];
  }
  __syncthreads();

  // ---- decoder: 2 barriers/step; BOTH roles' acc pairs split across phases.
  // Phase A (step t): L0 finishes accL0 += Wy*h1_{t-1} (+wc*s +x), pointwise
  //                   -> h0_t; L1 starts accL1 = b1 + Whh1d*h1_{t-1}, emitY.
  // Phase B (step t): L1 finishes accL1 += Wih1d*h0_t, pointwise -> h1_t;
  //                   L0 prefetches accL0 = E0d + Whh0d*h0_t for step t+1.
  // Accumulation order e0r -> Whh0d -> Wy -> wc*s -> x identical to R21.
  fx4 accL0[4], accL1[4];
  if (isL0){
    #pragma unroll
    for (int gg = 0; gg < 4; ++gg)
      #pragma unroll
      for (int r = 0; r < 4; ++r) accL0[gg][r] = e0r[gg][r];
    accK512_lds(accL0, h0A + hoff, smem, lane8);            // Whh0d * h0_287
  }
  #pragma unroll 1
  for (int t = 0; t < 288; ++t){
    if (isL0){
      // phase A: finish h0_t
      if (t > 0)
        accK512_lds(accL0, h1A + hoff, smem + 32768, lane8); // Wy * h1_{t-1}
      float s[4];
      #pragma unroll
      for (int r = 0; r < 4; ++r) s[r] = (t == 0) ? y0v[bq + r] : projB_val;
      float xv[4][6];
      #pragma unroll
      for (int r = 0; r < 4; ++r){
        const float* xr = xf + ((size_t)(bq + r)*288 + t)*6;
        #pragma unroll
        for (int kk = 0; kk < 6; ++kk) xv[r][kk] = xr[kk];
      }
      #pragma unroll
      for (int gg = 0; gg < 4; ++gg){
        #pragma unroll
        for (int r = 0; r < 4; ++r) accL0[gg][r] += wc[gg] * s[r];
        #pragma unroll
        for (int kk = 0; kk < 6; ++kk){
          float w = xw[gg][kk];
          #pragma unroll
          for (int r = 0; r < 4; ++r) accL0[gg][r] += w * xv[r][kk];
        }
      }
      pointwise(accL0, creg, bq, u, col, h0B);
    } else {
      // phase A: start accL1; emit y_{t-1}
      #pragma unroll
      for (int gg = 0; gg < 4; ++gg)
        #pragma unroll
        for (int r = 0; r < 4; ++r) accL1[gg][r] = b1r[gg];
      accK512_lds(accL1, h1A + hoff, smem + 32768, lane8);  // Whh1d * h1_{t-1}
      if (k < 36 && t > 0) emitY(h1A, t - 1);
    }
    if (groupbar(cntg, sub, ++gen, go, leader, abortf, &s_abort)) return;
    if (isL0){
      // phase B: prefetch accL0 for step t+1 (h0_t just published)
      if (t < 287){
        #pragma unroll
        for (int gg = 0; gg < 4; ++gg)
          #pragma unroll
          for (int r = 0; r < 4; ++r) accL0[gg][r] = e0r[gg][r];
        accK512_lds(accL0, h0B + hoff, smem, lane8);        // Whh0d * h0_t
      }
    } else {
      // phase B: finish h1_t
      accK512_lds(accL1, h0B + hoff, smem, lane8);          // Wih1d * h0_t
      pointwise(accL1, creg, bq, u, col, h1B);
    }
    if (groupbar(cntg, sub, ++gen, go, leader, abortf, &s_abort)) return;
    { uint16_t* t_ = h0A; h0A = h0B; h0B = t_; }
    { uint16_t* t_ = h1A; h1A = h1B; h1B = t_; }
  }

  // final y_287 (h1A = h1_287, published by last barrier)
  if (!isL0 && k < 36) emitY(h1A, 287);
}

// ---------------- prep: frag-ordered bf16 weights (+Wy), emb+bias folds ----
#define PREP_S 1048576
#define PREP_TOTAL (7*PREP_S + 1048576 + 6144)

__global__ void __launch_bounds__(256)
prep_kernel(const float* __restrict__ encWih0, const float* __restrict__ encWhh0,
            const float* __restrict__ encWih1, const float* __restrict__ encWhh1,
            const float* __restrict__ decWih0, const float* __restrict__ decWhh0,
            const float* __restrict__ decWih1, const float* __restrict__ decWhh1,
            const float* __restrict__ encbih0, const float* __restrict__ encbhh0,
            const float* __restrict__ encbih1, const float* __restrict__ encbhh1,
            const float* __restrict__ decbih0, const float* __restrict__ decbhh0,
            const float* __restrict__ decbih1, const float* __restrict__ decbhh1,
            const float* __restrict__ projW, const float* __restrict__ emb,
            const int* __restrict__ turb,
            uint16_t* Whh0e, uint16_t* Wih1e, uint16_t* Whh1e,
            uint16_t* Whh0d, uint16_t* Wih1d, uint16_t* Whh1d, uint16_t* Wyp,
            float* E0e, float* E0d, float* b1e, float* b1d, float* wcol0)
{
  int i = blockIdx.x*256 + threadIdx.x;
  if (i >= PREP_TOTAL) return;
  if (i < 7*PREP_S){
    // fragment reorder: dest = role*32768 + gate*8192 + kc*512 + lane*8 + j
    // value = W[gate*512 + role*16 + (lane&15)][kc*32 + (lane>>4)*8 + j]
    int w = i >> 20, r = i & (PREP_S - 1);
    int role = r >> 15;
    int rem  = r & 32767;
    int gate = rem >> 13;
    int kc   = (rem >> 9) & 15;
    int ln   = (rem >> 3) & 63;
    int j    = rem & 7;
    int c = ln & 15, q = ln >> 4;
    int row  = (gate << 9) + (role << 4) + c;
    int colk = (kc << 5) + (q << 3) + j;
    float v;
    if (w == 6){
      v = decWih0[(size_t)row*23] * projW[colk];     // Wy = wcol0 (x) projW
    } else {
      const float* src = (w==0)?encWhh0:(w==1)?encWih1:(w==2)?encWhh1:
                         (w==3)?decWhh0:(w==4)?decWih1:decWhh1;
      v = src[(size_t)row*512 + colk];
    }
    uint16_t* dst = (w==0)?Whh0e:(w==1)?Wih1e:(w==2)?Whh1e:
                    (w==3)?Whh0d:(w==4)?Wih1d:(w==5)?Whh1d:Wyp;
    dst[r] = f2bf(v);
  } else if (i < 7*PREP_S + 524288){
    int r = i - 7*PREP_S; int b = r >> 11, j = r & 2047;
    float s = encbih0[j] + encbhh0[j];
    const float* e = emb + (size_t)turb[b]*16;
    const float* wr = encWih0 + (size_t)j*24 + 8;
    #pragma unroll
    for (int m = 0; m < 16; ++m) s += e[m]*wr[m];
    E0e[r] = s;
  } else if (i < 7*PREP_S + 1048576){
    int r = i - 7*PREP_S - 524288; int b = r >> 11, j = r & 2047;
    float s = decbih0[j] + decbhh0[j];
    const float* e = emb + (size_t)turb[b]*16;
    const float* wr = decWih0 + (size_t)j*23 + 7;
    #pragma unroll
    for (int m = 0; m < 16; ++m) s += e[m]*wr[m];
    E0d[r] = s;
  } else {
    int r = i - 7*PREP_S - 1048576;
    if (r < 2048)      b1e[r] = encbih1[r] + encbhh1[r];
    else if (r < 4096){ int j = r - 2048; b1d[j] = decbih1[j] + decbhh1[j]; }
    else              { int j = r - 4096; wcol0[j] = decWih0[(size_t)j*23]; }
  }
}

// ---------------------------------------------------------------------------
extern "C" void kernel_launch(void* const* d_in, const int* in_sizes, int n_in,
                              void* d_out, int out_size, void* d_ws, size_t ws_size,
                              hipStream_t stream)
{
  const float* xh      = (const float*)d_in[0];
  const float* xf      = (const float*)d_in[1];
  const float* y0v     = (const float*)d_in[2];
  const int*   turb    = (const int*)d_in[3];
  const float* emb     = (const float*)d_in[5];
  const float* encWih0 = (const float*)d_in[6];
  const float* encWhh0 = (const float*)d_in[7];
  const float* encbih0 = (const float*)d_in[8];
  const float* encbhh0 = (const float*)d_in[9];
  const float* encWih1 = (const float*)d_in[10];
  const float* encWhh1 = (const float*)d_in[11];
  const float* encbih1 = (const float*)d_in[12];
  const float* encbhh1 = (const float*)d_in[13];
  const float* decWih0 = (const float*)d_in[14];
  const float* decWhh0 = (const float*)d_in[15];
  const float* decbih0 = (const float*)d_in[16];
  const float* decbhh0 = (const float*)d_in[17];
  const float* decWih1 = (const float*)d_in[18];
  const float* decWhh1 = (const float*)d_in[19];
  const float* decbih1 = (const float*)d_in[20];
  const float* decbhh1 = (const float*)d_in[21];
  const float* projW   = (const float*)d_in[22];
  const float* projB   = (const float*)d_in[23];
  float* out = (float*)d_out;

  char* ws = (char*)d_ws;
  constexpr size_t SZW = (size_t)2048*512*2;        // 2 MiB per matrix
  constexpr size_t OFF_Whh0e = 0;
  constexpr size_t OFF_Wih1e = SZW;
  constexpr size_t OFF_Whh1e = 2*SZW;
  constexpr size_t OFF_Whh0d = 3*SZW;
  constexpr size_t OFF_Wih1d = 4*SZW;
  constexpr size_t OFF_Whh1d = 5*SZW;
  constexpr size_t OFF_Wy    = 6*SZW;
  constexpr size_t OFF_E0e   = 7*SZW;
  constexpr size_t OFF_E0d   = OFF_E0e + 2097152;
  constexpr size_t OFF_b1e   = OFF_E0d + 2097152;
  constexpr size_t OFF_b1d   = OFF_b1e + 8192;
  constexpr size_t OFF_wcol0 = OFF_b1d + 8192;
  constexpr size_t OFF_h0    = OFF_wcol0 + 8192;
  constexpr size_t OFF_h1    = OFF_h0 + 524288;
  constexpr size_t OFF_cnt   = OFF_h1 + 524288;
  constexpr size_t ZERO_BYTES = 2*524288 + 2048;    // h0,h1 ping-pong + counters+go+abort

  uint16_t* Whh0e = (uint16_t*)(ws + OFF_Whh0e);
  uint16_t* Wih1e = (uint16_t*)(ws + OFF_Wih1e);
  uint16_t* Whh1e = (uint16_t*)(ws + OFF_Whh1e);
  uint16_t* Whh0d = (uint16_t*)(ws + OFF_Whh0d);
  uint16_t* Wih1d = (uint16_t*)(ws + OFF_Wih1d);
  uint16_t* Whh1d = (uint16_t*)(ws + OFF_Whh1d);
  uint16_t* Wyp   = (uint16_t*)(ws + OFF_Wy);
  float* E0e   = (float*)(ws + OFF_E0e);
  float* E0d   = (float*)(ws + OFF_E0d);
  float* b1e   = (float*)(ws + OFF_b1e);
  float* b1d   = (float*)(ws + OFF_b1d);
  float* wcol0 = (float*)(ws + OFF_wcol0);
  uint16_t* h0p = (uint16_t*)(ws + OFF_h0);
  uint16_t* h1p = (uint16_t*)(ws + OFF_h1);
  unsigned* cntp = (unsigned*)(ws + OFF_cnt);

  hipMemsetAsync(ws + OFF_h0, 0, ZERO_BYTES, stream);

  prep_kernel<<<dim3((PREP_TOTAL + 255)/256), dim3(256), 0, stream>>>(
      encWih0, encWhh0, encWih1, encWhh1, decWih0, decWhh0, decWih1, decWhh1,
      encbih0, encbhh0, encbih1, encbhh1, decbih0, decbhh0, decbih1, decbhh1,
      projW, emb, turb,
      Whh0e, Wih1e, Whh1e, Whh0d, Wih1d, Whh1d, Wyp,
      E0e, E0d, b1e, b1d, wcol0);

  // Plain launch (proven R11/R14/R15/R20/R21). 128 blocks on 256 CUs @
  // 1 block/CU -> co-residency with 2x slack; barrier spin is abort-guarded.
  seq2seq_main<<<dim3(NBLK), dim3(NTHR), 0, stream>>>(
      Whh0e, Wih1e, Whh1e, Whh0d, Wih1d, Whh1d, Wyp,
      E0e, E0d, b1e, b1d, wcol0,
      h0p, h1p, xh, xf, y0v,
      encWih0, decWih0, projW, projB,
      out, cntp);
}

// Round 17
// 7361.435 us; speedup vs baseline: 2.2677x; 1.0531x over previous
//
#include <hip/hip_runtime.h>
#include <stdint.h>

// ---------------------------------------------------------------------------
// R24 = R23 (7.75ms, best) scaled to FULL-GPU: 256 blocks x 256 threads.
//   R23 used 128 blocks (8 waves) on 256 CUs = half the GPU, a residency
//   insurance choice from R11 (post-R10 container death, which predates the
//   abort guard and is confounded with broker flakes seen in R3/R22).
//   With the abort guard, a true residency failure = ~65ms fast-fail with a
//   live container (resident blocks trip abortf; late blocks see it at their
//   first barrier and exit) -> the experiment is safe.
//   Geometry: 4 supergroups x 64 roles, 4 waves/block, 64 batch rows/group.
//   Per-block A-load volume halves -> cold-acc ~2.2us; compute on 256 CUs.
//   Counter arena: counters sg*128 (0..511), abort @512, go @544+sg*32;
//   zero region widened to 4KiB. Per-lane math identical to R23.
// R23 recap (all retained): decoder both-role split-acc (1 accK512 per role
//   per phase, VGPR-carried partials), leader/go barrier with load-based
//   detect + acquire-inv exit, system-scope packed h stores, plain b128
//   L2-shared h reads, LDS-resident frag weights, Wy rank-1 y-feedback,
//   emitY single-writer, abort-guarded spins, plain launch.
// ---------------------------------------------------------------------------

typedef __attribute__((ext_vector_type(8))) short bfx8;   // 8 bf16 (4 VGPRs)
typedef __attribute__((ext_vector_type(4))) float fx4;

#define NBLK 256
#define NTHR 256
#define BH   (256*512)

__device__ __forceinline__ unsigned short f2bf(float f){
  unsigned u = __float_as_uint(f);
  u += 0x7FFFu + ((u >> 16) & 1u);          // RNE
  return (unsigned short)(u >> 16);
}
__device__ __forceinline__ float bf2f(unsigned short b){
  return __uint_as_float(((unsigned)b) << 16);
}
__device__ __forceinline__ float sigm(float x){ return 1.0f/(1.0f + __expf(-x)); }
__device__ __forceinline__ float tanhf_(float x){
  x = fminf(12.0f, fmaxf(-12.0f, x));
  float e = __expf(2.0f*x);
  return (e - 1.0f)/(e + 1.0f);
}

// 64-block supergroup barrier, leader/go structure with load-based detect.
__device__ __forceinline__ bool groupbar(unsigned* cntg, int sub, unsigned gen,
                                         unsigned* go, bool leader,
                                         unsigned* abortf, volatile unsigned* s_abort){
  __syncthreads();
  if (threadIdx.x == 0){
    __hip_atomic_fetch_add(cntg + sub*32, 1u, __ATOMIC_RELAXED, __HIP_MEMORY_SCOPE_AGENT);
    const unsigned target = gen*16u;
    unsigned spins = 0;
    if (leader){
      for (;;){
        unsigned v0 = __hip_atomic_load(cntg +  0, __ATOMIC_RELAXED, __HIP_MEMORY_SCOPE_SYSTEM);
        unsigned v1 = __hip_atomic_load(cntg + 32, __ATOMIC_RELAXED, __HIP_MEMORY_SCOPE_SYSTEM);
        unsigned v2 = __hip_atomic_load(cntg + 64, __ATOMIC_RELAXED, __HIP_MEMORY_SCOPE_SYSTEM);
        unsigned v3 = __hip_atomic_load(cntg + 96, __ATOMIC_RELAXED, __HIP_MEMORY_SCOPE_SYSTEM);
        if (v0 >= target && v1 >= target && v2 >= target && v3 >= target) break;
        if (((++spins) & 1023u) == 0u){
          if (__hip_atomic_load(abortf, __ATOMIC_RELAXED, __HIP_MEMORY_SCOPE_AGENT) != 0u){
            *s_abort = 1u; break;
          }
          if (spins > (1u << 20)){
            __hip_atomic_store(abortf, 1u, __ATOMIC_RELAXED, __HIP_MEMORY_SCOPE_AGENT);
            *s_abort = 1u; break;
          }
        }
        __builtin_amdgcn_s_sleep(2);
      }
      __hip_atomic_store(go, gen, __ATOMIC_RELAXED, __HIP_MEMORY_SCOPE_SYSTEM);
    } else {
      while (__hip_atomic_load(go, __ATOMIC_RELAXED, __HIP_MEMORY_SCOPE_SYSTEM) < gen){
        if (((++spins) & 1023u) == 0u){
          if (__hip_atomic_load(abortf, __ATOMIC_RELAXED, __HIP_MEMORY_SCOPE_AGENT) != 0u){
            *s_abort = 1u; break;
          }
          if (spins > (1u << 20)){
            __hip_atomic_store(abortf, 1u, __ATOMIC_RELAXED, __HIP_MEMORY_SCOPE_AGENT);
            *s_abort = 1u; break;
          }
        }
        __builtin_amdgcn_s_sleep(2);
      }
    }
    (void)__hip_atomic_load(cntg, __ATOMIC_ACQUIRE, __HIP_MEMORY_SCOPE_AGENT);  // buffer_inv
  }
  __syncthreads();
  return *s_abort != 0u;
}

// K=512 accumulate: A rows from global h via PLAIN b128 loads (L2-cached,
// fresh after the barrier's inv); B = 4 gate-slices from LDS fragment layout.
__device__ __forceinline__ void accK512_lds(fx4* acc, const uint16_t* aq,
                                            const uint16_t* wl, int lane8){
  #pragma unroll
  for (int kc = 0; kc < 16; ++kc){
    bfx8 af = *(const bfx8*)(aq + kc*32);
    acc[0] = __builtin_amdgcn_mfma_f32_16x16x32_bf16(af, *(const bfx8*)(wl +         kc*512 + lane8), acc[0], 0, 0, 0);
    acc[1] = __builtin_amdgcn_mfma_f32_16x16x32_bf16(af, *(const bfx8*)(wl +  8192 + kc*512 + lane8), acc[1], 0, 0, 0);
    acc[2] = __builtin_amdgcn_mfma_f32_16x16x32_bf16(af, *(const bfx8*)(wl + 16384 + kc*512 + lane8), acc[2], 0, 0, 0);
    acc[3] = __builtin_amdgcn_mfma_f32_16x16x32_bf16(af, *(const bfx8*)(wl + 24576 + kc*512 + lane8), acc[3], 0, 0, 0);
  }
}

// LSTM pointwise; h store = packed 2-col SYSTEM-scope atomic dword.
__device__ __forceinline__ void pointwise(fx4* acc, fx4& creg, int bq, int u,
                                          int col, uint16_t* hout){
  #pragma unroll
  for (int r = 0; r < 4; ++r){
    float iv = sigm(acc[0][r]);
    float fv = sigm(acc[1][r]);
    float gv = tanhf_(acc[2][r]);
    float ov = sigm(acc[3][r]);
    float cn = fv * creg[r] + iv * gv;
    creg[r] = cn;
    unsigned hb = (unsigned)f2bf(ov * tanhf_(cn));
    unsigned nb = __shfl_xor(hb, 1);
    if ((col & 1) == 0){
      __hip_atomic_store((unsigned*)(hout + (size_t)(bq + r)*512 + u), hb | (nb << 16),
                         __ATOMIC_RELAXED, __HIP_MEMORY_SCOPE_SYSTEM);
    }
  }
}

__global__ void __launch_bounds__(NTHR)
seq2seq_main(const uint16_t* __restrict__ Whh0e, const uint16_t* __restrict__ Wih1e,
             const uint16_t* __restrict__ Whh1e, const uint16_t* __restrict__ Whh0d,
             const uint16_t* __restrict__ Wih1d, const uint16_t* __restrict__ Whh1d,
             const uint16_t* __restrict__ Wy,
             const float* __restrict__ E0e, const float* __restrict__ E0d,
             const float* __restrict__ b1e, const float* __restrict__ b1d,
             const float* __restrict__ wcol0,
             uint16_t* h0buf, uint16_t* h1buf,
             const float* __restrict__ xh, const float* __restrict__ xf,
             const float* __restrict__ y0v,
             const float* __restrict__ encWih0, const float* __restrict__ decWih0,
             const float* __restrict__ projW, const float* __restrict__ projB,
             float* out, unsigned* cntBase)
{
  __shared__ uint4 smem4[8192];                 // 128 KiB static LDS
  __shared__ unsigned s_abort;
  uint16_t* smem = (uint16_t*)smem4;

  const int tid  = threadIdx.x;
  const int lane = tid & 63;
  const int wvi  = tid >> 6;                    // wave in block, 0..3
  const int sg   = blockIdx.x >> 6;             // supergroup (64 batch rows), 0..3
  const int k    = blockIdx.x & 63;             // role: 0..31 L0, 32..63 L1
  const bool isL0 = (k < 32);
  const int role = isL0 ? k : k - 32;           // u-slice index, 0..31
  const int col  = lane & 15;
  const int quad = lane >> 4;
  const int rowbase = (sg << 6) + (wvi << 4);   // wave's 16-row M-tile base
  const int bq   = rowbase + (quad << 2);
  const int u    = (role << 4) + col;
  const int lane8 = lane << 3;
  unsigned* cntg = cntBase + (size_t)sg * 128;  // 4 counters x 128B / supergroup
  unsigned* abortf = cntBase + 512;             // abort flag (own line, zeroed)
  unsigned* go     = cntBase + 544 + sg*32;     // go word (own line, zeroed)
  const bool leader = (k == 0);
  const int sub  = k >> 4;
  unsigned gen = 0;
  fx4 creg = {0.f, 0.f, 0.f, 0.f};              // c0 (L0) or c1 (L1)
  const float projB_val = projB[0];
  const int hoff = (rowbase + col)*512 + (quad << 3);

  if (tid == 0) s_abort = 0u;

  uint16_t *h0A = h0buf, *h0B = h0buf + BH;
  uint16_t *h1A = h1buf, *h1B = h1buf + BH;

  // ---- stage encoder weight slices into LDS ----
  if (isL0){
    const uint4* s0 = (const uint4*)(Whh0e + (size_t)role*32768);
    for (int i = tid; i < 4096; i += NTHR) smem4[i] = s0[i];
  } else {
    const uint4* s0 = (const uint4*)(Wih1e + (size_t)role*32768);
    const uint4* s1 = (const uint4*)(Whh1e + (size_t)role*32768);
    for (int i = tid; i < 4096; i += NTHR){ smem4[i] = s0[i]; smem4[4096+i] = s1[i]; }
  }

  // ---- hoist per-lane constants into registers ----
  float e0r[4][4], xw[4][8], wc[4], b1r[4], pw8[8];
  if (isL0){
    #pragma unroll
    for (int gg = 0; gg < 4; ++gg){
      #pragma unroll
      for (int r = 0; r < 4; ++r)
        e0r[gg][r] = E0e[(size_t)(bq + r)*2048 + (gg << 9) + u];
      #pragma unroll
      for (int kk = 0; kk < 8; ++kk)
        xw[gg][kk] = encWih0[(size_t)((gg << 9) + u)*24 + kk];
    }
  } else {
    #pragma unroll
    for (int gg = 0; gg < 4; ++gg) b1r[gg] = b1e[(gg << 9) + u];
    if (k < 36){                                // emitY blocks k=32..35
      #pragma unroll
      for (int kk = 0; kk < 8; ++kk) pw8[kk] = projW[lane8 + kk];
    }
  }
  __syncthreads();

  auto encCompute = [&](int tt, const uint16_t* h0c, uint16_t* h0n){
    fx4 acc[4];
    #pragma unroll
    for (int gg = 0; gg < 4; ++gg)
      #pragma unroll
      for (int r = 0; r < 4; ++r) acc[gg][r] = e0r[gg][r];
    float xv[4][8];
    #pragma unroll
    for (int r = 0; r < 4; ++r){
      const float* xr = xh + ((size_t)(bq + r)*288 + tt)*8;
      #pragma unroll
      for (int kk = 0; kk < 8; ++kk) xv[r][kk] = xr[kk];
    }
    accK512_lds(acc, h0c + hoff, smem, lane8);
    #pragma unroll
    for (int gg = 0; gg < 4; ++gg)
      #pragma unroll
      for (int kk = 0; kk < 8; ++kk){
        float w = xw[gg][kk];
        #pragma unroll
        for (int r = 0; r < 4; ++r) acc[gg][r] += w * xv[r][kk];
      }
    pointwise(acc, creg, bq, u, col, h0n);
  };

  // emitY: blocks k=32..35 cover the supergroup's 64 rows (16 each); wave wvi
  // covers 4 rows. Plain loads (fresh after barrier inv); single-writer out.
  auto emitY = [&](const uint16_t* h1cur, int tt){
    int rb = (sg << 6) + ((k - 32) << 4) + (wvi << 2);
    #pragma unroll 1
    for (int j = 0; j < 4; ++j){
      int b = rb + j;
      const uint16_t* hr = h1cur + (size_t)b*512 + lane8;
      float part = 0.f;
      #pragma unroll
      for (int kk = 0; kk < 8; ++kk) part += bf2f(hr[kk]) * pw8[kk];
      #pragma unroll
      for (int off = 32; off > 0; off >>= 1) part += __shfl_down(part, off);
      if (lane == 0) out[(size_t)b*288 + tt] = part + projB_val;
    }
  };

  // ---- prologue: enc L0 t=0 (h_{-1}=0 via memset) ----
  if (isL0) encCompute(0, h0A, h0B);
  if (groupbar(cntg, sub, ++gen, go, leader, abortf, &s_abort)) return;
  { uint16_t* t_ = h0A; h0A = h0B; h0B = t_; }   // h0A = h0_0

  // ---- encoder: 1 barrier/step; L1_t || L0_{t+1} ----
  #pragma unroll 1
  for (int t = 0; t < 288; ++t){
    if (isL0){
      if (t < 287) encCompute(t + 1, h0A, h0B);
    } else {
      fx4 acc[4];
      #pragma unroll
      for (int gg = 0; gg < 4; ++gg)
        #pragma unroll
        for (int r = 0; r < 4; ++r) acc[gg][r] = b1r[gg];
      accK512_lds(acc, h0A + hoff, smem, lane8);            // Wih1e * h0_t
      accK512_lds(acc, h1A + hoff, smem + 32768, lane8);    // Whh1e * h1_{t-1}
      pointwise(acc, creg, bq, u, col, h1B);
    }
    if (groupbar(cntg, sub, ++gen, go, leader, abortf, &s_abort)) return;
    { uint16_t* t_ = h1A; h1A = h1B; h1B = t_; }
    if (t < 287){ uint16_t* t_ = h0A; h0A = h0B; h0B = t_; }
  }
  // h0A = h0_287, h1A = h1_287; c continues into decoder.

  // ---- restage decoder weights + regs (block-local) ----
  if (isL0){
    const uint4* s0 = (const uint4*)(Whh0d + (size_t)role*32768);
    const uint4* s1 = (const uint4*)(Wy    + (size_t)role*32768);
    for (int i = tid; i < 4096; i += NTHR){ smem4[i] = s0[i]; smem4[4096+i] = s1[i]; }
    #pragma unroll
    for (int gg = 0; gg < 4; ++gg){
      #pragma unroll
      for (int r = 0; r < 4; ++r)
        e0r[gg][r] = E0d[(size_t)(bq + r)*2048 + (gg << 9) + u];
      #pragma unroll
      for (int kk = 0; kk < 6; ++kk)
        xw[gg][kk] = decWih0[(size_t)((gg << 9) + u)*23 + 1 + kk];
      wc[gg] = wcol0[(gg << 9) + u];
    }
  } else {
    const uint4* s0 = (const uint4*)(Wih1d + (size_t)role*32768);
    const uint4* s1 = (const uint4*)(Whh1d + (size_t)role*32768);
    for (int i = tid; i < 4096; i += NTHR){ smem4[i] = s0[i]; smem4[4096+i] = s1[i]; }
    #pragma unroll
    for (int gg = 0; gg < 4; ++gg) b1r[gg] = b1d[(gg << 9) + u];
  }
  __syncthreads();

  // ---- decoder: 2 barriers/step; BOTH roles' acc pairs split across phases.
  // Phase A (step t): L0 finishes accL0 += Wy*h1_{t-1} (+wc*s +x), pointwise
  //                   -> h0_t; L1 starts accL1 = b1 + Whh1d*h1_{t-1}, emitY.
  // Phase B (step t): L1 finishes accL1 += Wih1d*h0_t, pointwise -> h1_t;
  //                   L0 prefetches accL0 = E0d + Whh0d*h0_t for step t+1.
  // Accumulation order e0r -> Whh0d -> Wy -> wc*s -> x identical to R23.
  fx4 accL0[4], accL1[4];
  if (isL0){
    #pragma unroll
    for (int gg = 0; gg < 4; ++gg)
      #pragma unroll
      for (int r = 0; r < 4; ++r) accL0[gg][r] = e0r[gg][r];
    accK512_lds(accL0, h0A + hoff, smem, lane8);            // Whh0d * h0_287
  }
  #pragma unroll 1
  for (int t = 0; t < 288; ++t){
    if (isL0){
      // phase A: finish h0_t
      if (t > 0)
        accK512_lds(accL0, h1A + hoff, smem + 32768, lane8); // Wy * h1_{t-1}
      float s[4];
      #pragma unroll
      for (int r = 0; r < 4; ++r) s[r] = (t == 0) ? y0v[bq + r] : projB_val;
      float xv[4][6];
      #pragma unroll
      for (int r = 0; r < 4; ++r){
        const float* xr = xf + ((size_t)(bq + r)*288 + t)*6;
        #pragma unroll
        for (int kk = 0; kk < 6; ++kk) xv[r][kk] = xr[kk];
      }
      #pragma unroll
      for (int gg = 0; gg < 4; ++gg){
        #pragma unroll
        for (int r = 0; r < 4; ++r) accL0[gg][r] += wc[gg] * s[r];
        #pragma unroll
        for (int kk = 0; kk < 6; ++kk){
          float w = xw[gg][kk];
          #pragma unroll
          for (int r = 0; r < 4; ++r) accL0[gg][r] += w * xv[r][kk];
        }
      }
      pointwise(accL0, creg, bq, u, col, h0B);
    } else {
      // phase A: start accL1; emit y_{t-1}
      #pragma unroll
      for (int gg = 0; gg < 4; ++gg)
        #pragma unroll
        for (int r = 0; r < 4; ++r) accL1[gg][r] = b1r[gg];
      accK512_lds(accL1, h1A + hoff, smem + 32768, lane8);  // Whh1d * h1_{t-1}
      if (k < 36 && t > 0) emitY(h1A, t - 1);
    }
    if (groupbar(cntg, sub, ++gen, go, leader, abortf, &s_abort)) return;
    if (isL0){
      // phase B: prefetch accL0 for step t+1 (h0_t just published)
      if (t < 287){
        #pragma unroll
        for (int gg = 0; gg < 4; ++gg)
          #pragma unroll
          for (int r = 0; r < 4; ++r) accL0[gg][r] = e0r[gg][r];
        accK512_lds(accL0, h0B + hoff, smem, lane8);        // Whh0d * h0_t
      }
    } else {
      // phase B: finish h1_t
      accK512_lds(accL1, h0B + hoff, smem, lane8);          // Wih1d * h0_t
      pointwise(accL1, creg, bq, u, col, h1B);
    }
    if (groupbar(cntg, sub, ++gen, go, leader, abortf, &s_abort)) return;
    { uint16_t* t_ = h0A; h0A = h0B; h0B = t_; }
    { uint16_t* t_ = h1A; h1A = h1B; h1B = t_; }
  }

  // final y_287 (h1A = h1_287, published by last barrier)
  if (!isL0 && k < 36) emitY(h1A, 287);
}

// ---------------- prep: frag-ordered bf16 weights (+Wy), emb+bias folds ----
#define PREP_S 1048576
#define PREP_TOTAL (7*PREP_S + 1048576 + 6144)

__global__ void __launch_bounds__(256)
prep_kernel(const float* __restrict__ encWih0, const float* __restrict__ encWhh0,
            const float* __restrict__ encWih1, const float* __restrict__ encWhh1,
            const float* __restrict__ decWih0, const float* __restrict__ decWhh0,
            const float* __restrict__ decWih1, const float* __restrict__ decWhh1,
            const float* __restrict__ encbih0, const float* __restrict__ encbhh0,
            const float* __restrict__ encbih1, const float* __restrict__ encbhh1,
            const float* __restrict__ decbih0, const float* __restrict__ decbhh0,
            const float* __restrict__ decbih1, const float* __restrict__ decbhh1,
            const float* __restrict__ projW, const float* __restrict__ emb,
            const int* __restrict__ turb,
            uint16_t* Whh0e, uint16_t* Wih1e, uint16_t* Whh1e,
            uint16_t* Whh0d, uint16_t* Wih1d, uint16_t* Whh1d, uint16_t* Wyp,
            float* E0e, float* E0d, float* b1e, float* b1d, float* wcol0)
{
  int i = blockIdx.x*256 + threadIdx.x;
  if (i >= PREP_TOTAL) return;
  if (i < 7*PREP_S){
    // fragment reorder: dest = role*32768 + gate*8192 + kc*512 + lane*8 + j
    // value = W[gate*512 + role*16 + (lane&15)][kc*32 + (lane>>4)*8 + j]
    int w = i >> 20, r = i & (PREP_S - 1);
    int role = r >> 15;
    int rem  = r & 32767;
    int gate = rem >> 13;
    int kc   = (rem >> 9) & 15;
    int ln   = (rem >> 3) & 63;
    int j    = rem & 7;
    int c = ln & 15, q = ln >> 4;
    int row  = (gate << 9) + (role << 4) + c;
    int colk = (kc << 5) + (q << 3) + j;
    float v;
    if (w == 6){
      v = decWih0[(size_t)row*23] * projW[colk];     // Wy = wcol0 (x) projW
    } else {
      const float* src = (w==0)?encWhh0:(w==1)?encWih1:(w==2)?encWhh1:
                         (w==3)?decWhh0:(w==4)?decWih1:decWhh1;
      v = src[(size_t)row*512 + colk];
    }
    uint16_t* dst = (w==0)?Whh0e:(w==1)?Wih1e:(w==2)?Whh1e:
                    (w==3)?Whh0d:(w==4)?Wih1d:(w==5)?Whh1d:Wyp;
    dst[r] = f2bf(v);
  } else if (i < 7*PREP_S + 524288){
    int r = i - 7*PREP_S; int b = r >> 11, j = r & 2047;
    float s = encbih0[j] + encbhh0[j];
    const float* e = emb + (size_t)turb[b]*16;
    const float* wr = encWih0 + (size_t)j*24 + 8;
    #pragma unroll
    for (int m = 0; m < 16; ++m) s += e[m]*wr[m];
    E0e[r] = s;
  } else if (i < 7*PREP_S + 1048576){
    int r = i - 7*PREP_S - 524288; int b = r >> 11, j = r & 2047;
    float s = decbih0[j] + decbhh0[j];
    const float* e = emb + (size_t)turb[b]*16;
    const float* wr = decWih0 + (size_t)j*23 + 7;
    #pragma unroll
    for (int m = 0; m < 16; ++m) s += e[m]*wr[m];
    E0d[r] = s;
  } else {
    int r = i - 7*PREP_S - 1048576;
    if (r < 2048)      b1e[r] = encbih1[r] + encbhh1[r];
    else if (r < 4096){ int j = r - 2048; b1d[j] = decbih1[j] + decbhh1[j]; }
    else              { int j = r - 4096; wcol0[j] = decWih0[(size_t)j*23]; }
  }
}

// ---------------------------------------------------------------------------
extern "C" void kernel_launch(void* const* d_in, const int* in_sizes, int n_in,
                              void* d_out, int out_size, void* d_ws, size_t ws_size,
                              hipStream_t stream)
{
  const float* xh      = (const float*)d_in[0];
  const float* xf      = (const float*)d_in[1];
  const float* y0v     = (const float*)d_in[2];
  const int*   turb    = (const int*)d_in[3];
  const float* emb     = (const float*)d_in[5];
  const float* encWih0 = (const float*)d_in[6];
  const float* encWhh0 = (const float*)d_in[7];
  const float* encbih0 = (const float*)d_in[8];
  const float* encbhh0 = (const float*)d_in[9];
  const float* encWih1 = (const float*)d_in[10];
  const float* encWhh1 = (const float*)d_in[11];
  const float* encbih1 = (const float*)d_in[12];
  const float* encbhh1 = (const float*)d_in[13];
  const float* decWih0 = (const float*)d_in[14];
  const float* decWhh0 = (const float*)d_in[15];
  const float* decbih0 = (const float*)d_in[16];
  const float* decbhh0 = (const float*)d_in[17];
  const float* decWih1 = (const float*)d_in[18];
  const float* decWhh1 = (const float*)d_in[19];
  const float* decbih1 = (const float*)d_in[20];
  const float* decbhh1 = (const float*)d_in[21];
  const float* projW   = (const float*)d_in[22];
  const float* projB   = (const float*)d_in[23];
  float* out = (float*)d_out;

  char* ws = (char*)d_ws;
  constexpr size_t SZW = (size_t)2048*512*2;        // 2 MiB per matrix
  constexpr size_t OFF_Whh0e = 0;
  constexpr size_t OFF_Wih1e = SZW;
  constexpr size_t OFF_Whh1e = 2*SZW;
  constexpr size_t OFF_Whh0d = 3*SZW;
  constexpr size_t OFF_Wih1d = 4*SZW;
  constexpr size_t OFF_Whh1d = 5*SZW;
  constexpr size_t OFF_Wy    = 6*SZW;
  constexpr size_t OFF_E0e   = 7*SZW;
  constexpr size_t OFF_E0d   = OFF_E0e + 2097152;
  constexpr size_t OFF_b1e   = OFF_E0d + 2097152;
  constexpr size_t OFF_b1d   = OFF_b1e + 8192;
  constexpr size_t OFF_wcol0 = OFF_b1d + 8192;
  constexpr size_t OFF_h0    = OFF_wcol0 + 8192;
  constexpr size_t OFF_h1    = OFF_h0 + 524288;
  constexpr size_t OFF_cnt   = OFF_h1 + 524288;
  constexpr size_t ZERO_BYTES = 2*524288 + 4096;    // h0,h1 ping-pong + 4-sg counter arena

  uint16_t* Whh0e = (uint16_t*)(ws + OFF_Whh0e);
  uint16_t* Wih1e = (uint16_t*)(ws + OFF_Wih1e);
  uint16_t* Whh1e = (uint16_t*)(ws + OFF_Whh1e);
  uint16_t* Whh0d = (uint16_t*)(ws + OFF_Whh0d);
  uint16_t* Wih1d = (uint16_t*)(ws + OFF_Wih1d);
  uint16_t* Whh1d = (uint16_t*)(ws + OFF_Whh1d);
  uint16_t* Wyp   = (uint16_t*)(ws + OFF_Wy);
  float* E0e   = (float*)(ws + OFF_E0e);
  float* E0d   = (float*)(ws + OFF_E0d);
  float* b1e   = (float*)(ws + OFF_b1e);
  float* b1d   = (float*)(ws + OFF_b1d);
  float* wcol0 = (float*)(ws + OFF_wcol0);
  uint16_t* h0p = (uint16_t*)(ws + OFF_h0);
  uint16_t* h1p = (uint16_t*)(ws + OFF_h1);
  unsigned* cntp = (unsigned*)(ws + OFF_cnt);

  hipMemsetAsync(ws + OFF_h0, 0, ZERO_BYTES, stream);

  prep_kernel<<<dim3((PREP_TOTAL + 255)/256), dim3(256), 0, stream>>>(
      encWih0, encWhh0, encWih1, encWhh1, decWih0, decWhh0, decWih1, decWhh1,
      encbih0, encbhh0, encbih1, encbhh1, decbih0, decbhh0, decbih1, decbhh1,
      projW, emb, turb,
      Whh0e, Wih1e, Whh1e, Whh0d, Wih1d, Whh1d, Wyp,
      E0e, E0d, b1e, b1d, wcol0);

  // Plain launch: 256 blocks x 256 thr x 128KiB LDS -> 1 block/CU, full GPU.
  // Residency failure cannot wedge: abort guard trips in ~65ms, resident
  // blocks drain, late blocks see abortf at their first barrier and exit.
  seq2seq_main<<<dim3(NBLK), dim3(NTHR), 0, stream>>>(
      Whh0e, Wih1e, Whh1e, Whh0d, Wih1d, Whh1d, Wyp,
      E0e, E0d, b1e, b1d, wcol0,
      h0p, h1p, xh, xf, y0v,
      encWih0, decWih0, projW, projB,
      out, cntp);
}